// Round 4
// baseline (1542.835 us; speedup 1.0000x reference)
//
#include <hip/hip_runtime.h>

#define B_  8
#define N_  4096
#define S_  1024
#define K_  64
#define CF_ 128
#define M_  (B_*S_*K_)   // 524288 rows per layer

typedef __attribute__((ext_vector_type(8))) short bshort8;
typedef __attribute__((ext_vector_type(4))) float f32x4;

__device__ __forceinline__ unsigned short f2bf(float f){
  unsigned int u = __float_as_uint(f);
  u = u + 0x7FFFu + ((u >> 16) & 1u);      // RTNE
  return (unsigned short)(u >> 16);
}
__device__ __forceinline__ float bf2f(unsigned short h){
  return __uint_as_float(((unsigned int)h) << 16);
}

// ---------------------------------------------------------------------------
// FPS: one block per batch. Bitwise-matches the reference (VERIFIED round 2/3:
// Output 0 passes): d = ((dx*dx)+(dy*dy))+(dz*dz) with plain rn ops (no FMA),
// min-accumulate, argmax with first-index tie-break. DO NOT TOUCH.
// ---------------------------------------------------------------------------
__global__ __launch_bounds__(256) void fps_kernel(const float* __restrict__ xyz,
                                                  float* __restrict__ nx_out,
                                                  float* __restrict__ nx_ws){
  __shared__ float sx[N_], sy[N_], sz[N_];
  __shared__ float wval[4];
  __shared__ int   widx[4];
  const int b = blockIdx.x, t = threadIdx.x;
  const float* xb = xyz + (size_t)b*N_*3;
  float px[16], py[16], pz[16], dist[16];
#pragma unroll
  for (int j=0;j<16;++j){
    int i = j*256 + t;
    px[j] = xb[i*3+0]; py[j] = xb[i*3+1]; pz[j] = xb[i*3+2];
    dist[j] = 1e10f;
    sx[i]=px[j]; sy[i]=py[j]; sz[i]=pz[j];
  }
  __syncthreads();
  int farthest = 0;
  const int lane = t & 63, w = t >> 6;
  for (int it=0; it<S_; ++it){
    float cx = sx[farthest], cy = sy[farthest], cz = sz[farthest];
    if (t==0){
      float* o  = nx_out + (size_t)(b*S_+it)*3;
      o[0]=cx; o[1]=cy; o[2]=cz;
      float* o2 = nx_ws + (size_t)(b*S_+it)*3;
      o2[0]=cx; o2[1]=cy; o2[2]=cz;
    }
    float best = -1.0f; int bidx = 0;
#pragma unroll
    for (int j=0;j<16;++j){
      float dx = __fsub_rn(px[j],cx), dy = __fsub_rn(py[j],cy), dz = __fsub_rn(pz[j],cz);
      float d  = __fadd_rn(__fadd_rn(__fmul_rn(dx,dx),__fmul_rn(dy,dy)),__fmul_rn(dz,dz));
      float nd = fminf(dist[j], d);
      dist[j] = nd;
      if (nd > best){ best = nd; bidx = j*256 + t; }
    }
#pragma unroll
    for (int m=1;m<64;m<<=1){
      float ov = __shfl_xor(best, m, 64);
      int   oi = __shfl_xor(bidx, m, 64);
      if (ov > best || (ov == best && oi < bidx)){ best = ov; bidx = oi; }
    }
    if (lane==0){ wval[w]=best; widx[w]=bidx; }
    __syncthreads();
    best = wval[0]; bidx = widx[0];
#pragma unroll
    for (int w2=1;w2<4;++w2){
      float ov = wval[w2]; int oi = widx[w2];
      if (ov > best || (ov == best && oi < bidx)){ best = ov; bidx = oi; }
    }
    farthest = bidx;
    __syncthreads();
  }
}

// ---------------------------------------------------------------------------
// Ball query: one wave per (b,s); ascending first-64 indices, pad with first.
// ROUND-4 FIX: two f32 op-order variants failed with IDENTICAL absmax ->
// the golden np reference evaluates in float64. Compute d in f64 (products of
// f32 are exact in f64; residual ~1e-16 << any op-order delta) and compare
// against 0.2*0.2 evaluated in f64 (= Python's 0.2**2).
// ---------------------------------------------------------------------------
__global__ __launch_bounds__(256) void qbp_kernel(const float* __restrict__ xyz,
                                                  const float* __restrict__ nx,
                                                  int* __restrict__ gi){
  const double R2 = 0.2*0.2;   // 0.04000000000000001 (f64)
  int gtid = blockIdx.x*256 + threadIdx.x;
  int wid = gtid >> 6, lane = gtid & 63;
  int b = wid >> 10, s = wid & 1023;
  const float* xb = xyz + (size_t)b*N_*3;
  const float* c  = nx + (size_t)(b*S_+s)*3;
  double cx=(double)c[0], cy=(double)c[1], cz=(double)c[2];
  double cc = cx*cx + cy*cy + cz*cz;
  int* g = gi + (size_t)(b*S_+s)*K_;
  int count = 0, first = -1;
  for (int ch=0; ch<64 && count<K_; ++ch){
    int i = ch*64 + lane;
    double x = (double)xb[i*3+0], y = (double)xb[i*3+1], z = (double)xb[i*3+2];
    double e  = cx*x + cy*y + cz*z;
    double pp = x*x + y*y + z*z;
    double d  = -2.0*e + cc + pp;
    bool keep = !(d > R2);
    unsigned long long bal = __ballot(keep);
    int pos = count + __builtin_popcountll(bal & ((1ull<<lane)-1ull));
    if (keep && pos < K_) g[pos] = i;
    if (first < 0 && bal) first = ch*64 + (int)__builtin_ctzll(bal);
    count += __builtin_popcountll(bal);
  }
  if (count < K_){
    int p = count + lane;
    if (p < K_) g[p] = first;
  }
}

// ---------------------------------------------------------------------------
// features (B,128,4096) f32 -> featT (B,4096,128) bf16
// ---------------------------------------------------------------------------
__global__ __launch_bounds__(256) void transpose_kernel(const float* __restrict__ f,
                                                        unsigned short* __restrict__ ft){
  __shared__ float tile[32][33];
  int b = blockIdx.z, ct = blockIdx.y, nt = blockIdx.x;
  int tx = threadIdx.x & 31, ty = threadIdx.x >> 5;
#pragma unroll
  for (int r=0; r<32; r+=8)
    tile[ty+r][tx] = f[((size_t)(b*128 + ct*32 + ty + r))*4096 + nt*32 + tx];
  __syncthreads();
#pragma unroll
  for (int r=0; r<32; r+=8){
    int n = nt*32 + ty + r, cc = ct*32 + tx;
    ft[((size_t)b*4096 + n)*128 + cc] = f2bf(tile[tx][ty+r]);
  }
}

// ---------------------------------------------------------------------------
// Weights -> bf16 [n][k]; layer-1 K permuted to [feat(0..127), dxyz(128..130), 0-pad..159]
// ---------------------------------------------------------------------------
__global__ void wprep_kernel(const float* __restrict__ W1, const float* __restrict__ W2,
                             const float* __restrict__ W3,
                             unsigned short* __restrict__ Wt1, unsigned short* __restrict__ Wt2,
                             unsigned short* __restrict__ Wt3){
  int t = blockIdx.x*blockDim.x + threadIdx.x;
  int stride = gridDim.x*blockDim.x;
  for (int idx=t; idx<128*160; idx+=stride){
    int n = idx/160, k = idx-(idx/160)*160;
    float v = 0.f;
    if (k < 128) v = W1[(k+3)*128 + n];
    else if (k < 131) v = W1[(k-128)*128 + n];
    Wt1[idx] = f2bf(v);
  }
  for (int idx=t; idx<128*128; idx+=stride){
    int n = idx>>7, k = idx&127;
    Wt2[idx] = f2bf(W2[k*128+n]);
  }
  for (int idx=t; idx<256*128; idx+=stride){
    int n = idx>>7, k = idx&127;
    Wt3[idx] = f2bf(W3[k*256+n]);
  }
}

// ---------------------------------------------------------------------------
// Fused recompute GEMM chain per 128-row slab. No y1/y2 in global memory.
// PHASE 1: GEMM1 -> col sums1
// PHASE 2: GEMM1 -> BN1+ReLU(LDS) -> GEMM2 -> col sums2
// PHASE 3: GEMM1 -> BN1 -> GEMM2 -> BN2 -> GEMM3 (2 N-halves) -> sums3 + min/max over K
// ---------------------------------------------------------------------------
template<int PHASE>
__global__ __launch_bounds__(256,2) void mm_fused(
    const unsigned short* __restrict__ featT,
    const unsigned short* __restrict__ Wt1,
    const unsigned short* __restrict__ Wt2,
    const unsigned short* __restrict__ Wt3,
    const int* __restrict__ gi,
    const float* __restrict__ xyz,
    const float* __restrict__ nxyz,
    const float* __restrict__ ss1,
    const float* __restrict__ ss2,
    float* __restrict__ slots,
    float* __restrict__ minv,
    float* __restrict__ maxv)
{
  __shared__ alignas(16) unsigned short At[128*40];
  __shared__ alignas(16) unsigned short Bt[128*40];
  __shared__ alignas(16) unsigned short Y[(PHASE>=2)?(128*136):16];
  __shared__ int giL[128];

  const int t = threadIdx.x;
  const int mblk = blockIdx.x;
  const int b = mblk >> 9;                 // 512 slabs per batch
  const int lane = t&63, wave = t>>6;
  const int wm = wave>>1, wn = wave&1;
  const int lrow = lane&15, quad = lane>>4;
  const int slot = mblk & 63;

  if (t<128) giL[t] = gi[(size_t)mblk*128 + t];
  __syncthreads();

  f32x4 acc[4][4];
  const f32x4 z4 = {0.f,0.f,0.f,0.f};
#pragma unroll
  for (int i=0;i<4;++i)
#pragma unroll
    for (int j=0;j<4;++j) acc[i][j]=z4;

  // ---------------- GEMM1: A = gathered [feat | dxyz | pad], K=160 ----------
  for (int ch=0; ch<5; ++ch){
#pragma unroll
    for (int half=0; half<2; ++half){
      int sl = t + half*256; int r = sl>>2, p = sl&3;
      *(bshort8*)&Bt[r*40+p*8] = *(const bshort8*)(Wt1 + r*160 + ch*32 + p*8);
      if (ch < 4){
        int i = giL[r];
        *(bshort8*)&At[r*40+p*8] =
            *(const bshort8*)(featT + ((size_t)b*N_ + i)*CF_ + ch*32 + p*8);
      } else {
        union { bshort8 v; unsigned short u[8]; } o;
#pragma unroll
        for (int e=0;e<8;++e) o.u[e]=0;
        if (p==0){
          int i = giL[r];
          int s = ((mblk*128 + r) >> 6) & 1023;
          const float* pp = xyz  + ((size_t)b*N_ + i)*3;
          const float* qq = nxyz + (size_t)(b*S_ + s)*3;
          o.u[0] = f2bf(__fsub_rn(pp[0],qq[0]));
          o.u[1] = f2bf(__fsub_rn(pp[1],qq[1]));
          o.u[2] = f2bf(__fsub_rn(pp[2],qq[2]));
        }
        *(bshort8*)&At[r*40+p*8] = o.v;
      }
    }
    __syncthreads();
    bshort8 af[4], bfr[4];
#pragma unroll
    for (int mt=0; mt<4; ++mt) af[mt]  = *(const bshort8*)&At[(wm*64+mt*16+lrow)*40 + quad*8];
#pragma unroll
    for (int nt=0; nt<4; ++nt) bfr[nt] = *(const bshort8*)&Bt[(wn*64+nt*16+lrow)*40 + quad*8];
#pragma unroll
    for (int mt=0; mt<4; ++mt)
#pragma unroll
      for (int nt=0; nt<4; ++nt)
        acc[mt][nt] = __builtin_amdgcn_mfma_f32_16x16x32_bf16(af[mt], bfr[nt], acc[mt][nt], 0,0,0);
    __syncthreads();
  }

  if constexpr (PHASE==1){
#pragma unroll
    for (int nt=0; nt<4; ++nt){
      float s=0.f, s2=0.f;
#pragma unroll
      for (int mt=0; mt<4; ++mt)
#pragma unroll
        for (int r=0; r<4; ++r){ float v=acc[mt][nt][r]; s+=v; s2=fmaf(v,v,s2); }
      s  += __shfl_xor(s,16,64);  s  += __shfl_xor(s,32,64);
      s2 += __shfl_xor(s2,16,64); s2 += __shfl_xor(s2,32,64);
      if (lane<16){
        int c = wn*64+nt*16+lane;
        atomicAdd(&slots[(slot*128+c)*2+0], s);
        atomicAdd(&slots[(slot*128+c)*2+1], s2);
      }
    }
    return;
  }

  if constexpr (PHASE>=2){
    // ---- BN1 + ReLU -> Y (C-layout: col=lane&15, row=quad*4+reg) ----
#pragma unroll
    for (int nt=0; nt<4; ++nt){
      int c = wn*64+nt*16+lrow;
      float sc = ss1[c], sh = ss1[128+c];
#pragma unroll
      for (int mt=0; mt<4; ++mt)
#pragma unroll
        for (int r=0; r<4; ++r){
          int row = wm*64+mt*16+quad*4+r;
          Y[row*136 + c] = f2bf(fmaxf(fmaf(acc[mt][nt][r], sc, sh), 0.f));
        }
    }
    __syncthreads();

    // ---------------- GEMM2: A = Y (z1), K=128 ----------------
#pragma unroll
    for (int i=0;i<4;++i)
#pragma unroll
      for (int j=0;j<4;++j) acc[i][j]=z4;
    for (int ch=0; ch<4; ++ch){
#pragma unroll
      for (int half=0; half<2; ++half){
        int sl = t + half*256; int r = sl>>2, p = sl&3;
        *(bshort8*)&Bt[r*40+p*8] = *(const bshort8*)(Wt2 + r*128 + ch*32 + p*8);
      }
      __syncthreads();
      bshort8 af[4], bfr[4];
#pragma unroll
      for (int mt=0; mt<4; ++mt) af[mt]  = *(const bshort8*)&Y[(wm*64+mt*16+lrow)*136 + ch*32 + quad*8];
#pragma unroll
      for (int nt=0; nt<4; ++nt) bfr[nt] = *(const bshort8*)&Bt[(wn*64+nt*16+lrow)*40 + quad*8];
#pragma unroll
      for (int mt=0; mt<4; ++mt)
#pragma unroll
        for (int nt=0; nt<4; ++nt)
          acc[mt][nt] = __builtin_amdgcn_mfma_f32_16x16x32_bf16(af[mt], bfr[nt], acc[mt][nt], 0,0,0);
      __syncthreads();
    }
  }

  if constexpr (PHASE==2){
#pragma unroll
    for (int nt=0; nt<4; ++nt){
      float s=0.f, s2=0.f;
#pragma unroll
      for (int mt=0; mt<4; ++mt)
#pragma unroll
        for (int r=0; r<4; ++r){ float v=acc[mt][nt][r]; s+=v; s2=fmaf(v,v,s2); }
      s  += __shfl_xor(s,16,64);  s  += __shfl_xor(s,32,64);
      s2 += __shfl_xor(s2,16,64); s2 += __shfl_xor(s2,32,64);
      if (lane<16){
        int c = wn*64+nt*16+lane;
        atomicAdd(&slots[(slot*128+c)*2+0], s);
        atomicAdd(&slots[(slot*128+c)*2+1], s2);
      }
    }
    return;
  }

  if constexpr (PHASE==3){
    // ---- BN2 + ReLU -> Y (overwrite) ----
#pragma unroll
    for (int nt=0; nt<4; ++nt){
      int c = wn*64+nt*16+lrow;
      float sc = ss2[c], sh = ss2[128+c];
#pragma unroll
      for (int mt=0; mt<4; ++mt)
#pragma unroll
        for (int r=0; r<4; ++r){
          int row = wm*64+mt*16+quad*4+r;
          Y[row*136 + c] = f2bf(fmaxf(fmaf(acc[mt][nt][r], sc, sh), 0.f));
        }
    }
    __syncthreads();

    // ---------------- GEMM3: A = Y (z2), Nout=256 in two halves ------------
    for (int h=0; h<2; ++h){
#pragma unroll
      for (int i=0;i<4;++i)
#pragma unroll
        for (int j=0;j<4;++j) acc[i][j]=z4;
      for (int ch=0; ch<4; ++ch){
#pragma unroll
        for (int half=0; half<2; ++half){
          int sl = t + half*256; int r = sl>>2, p = sl&3;
          *(bshort8*)&Bt[r*40+p*8] =
              *(const bshort8*)(Wt3 + ((size_t)(h*128+r))*128 + ch*32 + p*8);
        }
        __syncthreads();
        bshort8 af[4], bfr[4];
#pragma unroll
        for (int mt=0; mt<4; ++mt) af[mt]  = *(const bshort8*)&Y[(wm*64+mt*16+lrow)*136 + ch*32 + quad*8];
#pragma unroll
        for (int nt=0; nt<4; ++nt) bfr[nt] = *(const bshort8*)&Bt[(wn*64+nt*16+lrow)*40 + quad*8];
#pragma unroll
        for (int mt=0; mt<4; ++mt)
#pragma unroll
          for (int nt=0; nt<4; ++nt)
            acc[mt][nt] = __builtin_amdgcn_mfma_f32_16x16x32_bf16(af[mt], bfr[nt], acc[mt][nt], 0,0,0);
        __syncthreads();
      }
      // epilogue: sums3 + per-(b,s) min/max over the 64 rows of each group
#pragma unroll
      for (int nt=0; nt<4; ++nt){
        float s=0.f, s2=0.f, mx=-3.0e38f, mn=3.0e38f;
#pragma unroll
        for (int mt=0; mt<4; ++mt)
#pragma unroll
          for (int r=0; r<4; ++r){
            float v=acc[mt][nt][r];
            s+=v; s2=fmaf(v,v,s2);
            mx=fmaxf(mx,v); mn=fminf(mn,v);
          }
        s  += __shfl_xor(s,16,64);  s  += __shfl_xor(s,32,64);
        s2 += __shfl_xor(s2,16,64); s2 += __shfl_xor(s2,32,64);
        mx = fmaxf(mx, __shfl_xor(mx,16,64)); mx = fmaxf(mx, __shfl_xor(mx,32,64));
        mn = fminf(mn, __shfl_xor(mn,16,64)); mn = fminf(mn, __shfl_xor(mn,32,64));
        if (lane<16){
          int c = h*128 + wn*64+nt*16+lane;
          atomicAdd(&slots[(slot*256+c)*2+0], s);
          atomicAdd(&slots[(slot*256+c)*2+1], s2);
          size_t sidx = (size_t)mblk*2 + wm;         // global (b*1024+s)
          maxv[sidx*256 + c] = mx;
          minv[sidx*256 + c] = mn;
        }
      }
    }
  }
}

// ---------------------------------------------------------------------------
// Reduce 64 partial-sum slots -> per-channel scale/shift
// ---------------------------------------------------------------------------
__global__ void stats_kernel(const float* __restrict__ slots, const float* __restrict__ g,
                             const float* __restrict__ beta, float* __restrict__ ssOut,
                             int C, float inv_cnt){
  int c = threadIdx.x;
  if (c >= C) return;
  float s=0.f, s2=0.f;
  for (int k=0;k<64;++k){
    s  += slots[(k*C + c)*2 + 0];
    s2 += slots[(k*C + c)*2 + 1];
  }
  float m = s * inv_cnt;
  float v = fmaxf(s2 * inv_cnt - m*m, 0.f);
  float sc = rsqrtf(v + 1e-5f) * g[c];
  ssOut[c] = sc;
  ssOut[C + c] = beta[c] - m*sc;
}

// ---------------------------------------------------------------------------
// BN3 affine + relu on per-group max (min if scale<0); LDS-transposed so both
// the min/max reads and the (b,c,s)-layout writes are coalesced.
// ---------------------------------------------------------------------------
__global__ __launch_bounds__(256) void final_kernel(const float* __restrict__ minv,
                                                    const float* __restrict__ maxv,
                                                    const float* __restrict__ ss3,
                                                    float* __restrict__ out){
  __shared__ float tile[64][65];
  const int t = threadIdx.x;
  const int cb = blockIdx.x;   // 0..3  (64-channel block)
  const int sb = blockIdx.y;   // 0..15 (64-sample block)
  const int b  = blockIdx.z;   // 0..7
  const int w = t>>6, l = t&63;
  {
    int c = cb*64 + l;
    float sc = ss3[c], sh = ss3[256+c];
#pragma unroll
    for (int k=0;k<16;++k){
      int sl = k*4 + w;
      size_t mi = ((size_t)(b*1024 + sb*64 + sl))*256 + c;
      float v = (sc >= 0.f) ? maxv[mi] : minv[mi];
      tile[sl][l] = fmaxf(fmaf(v, sc, sh), 0.f);
    }
  }
  __syncthreads();
#pragma unroll
  for (int k=0;k<16;++k){
    int cl = k*4 + w;
    out[((size_t)(b*256 + cb*64 + cl))*1024 + sb*64 + l] = tile[l][cl];
  }
}

// ---------------------------------------------------------------------------
extern "C" void kernel_launch(void* const* d_in, const int* in_sizes, int n_in,
                              void* d_out, int out_size, void* d_ws, size_t ws_size,
                              hipStream_t stream){
  const float* xyz      = (const float*)d_in[0];
  const float* features = (const float*)d_in[1];
  const float* W1 = (const float*)d_in[2];
  const float* g1 = (const float*)d_in[3];
  const float* b1 = (const float*)d_in[4];
  const float* W2 = (const float*)d_in[5];
  const float* g2 = (const float*)d_in[6];
  const float* b2 = (const float*)d_in[7];
  const float* W3 = (const float*)d_in[8];
  const float* g3 = (const float*)d_in[9];
  const float* b3 = (const float*)d_in[10];
  float* out = (float*)d_out;

  char* ws = (char*)d_ws;
  size_t off = 0;
  auto alloc = [&](size_t bytes)->char*{
    char* p = ws + off;
    off = (off + bytes + 255) & ~(size_t)255;
    return p;
  };
  // total ~28 MB
  float* slots1 = (float*)alloc((size_t)64*128*2*4);
  float* slots2 = (float*)alloc((size_t)64*128*2*4);
  float* slots3 = (float*)alloc((size_t)64*256*2*4);
  float* ss1    = (float*)alloc(256*4);
  float* ss2    = (float*)alloc(256*4);
  float* ss3    = (float*)alloc(512*4);
  float* nxyz   = (float*)alloc((size_t)24576*4);
  int*   gi     = (int*)  alloc((size_t)M_*4);
  unsigned short* featT = (unsigned short*)alloc((size_t)B_*N_*CF_*2);
  unsigned short* Wt1   = (unsigned short*)alloc((size_t)128*160*2);
  unsigned short* Wt2   = (unsigned short*)alloc((size_t)128*128*2);
  unsigned short* Wt3   = (unsigned short*)alloc((size_t)256*128*2);
  float* minv = (float*)alloc((size_t)B_*S_*256*4);
  float* maxv = (float*)alloc((size_t)B_*S_*256*4);

  // zero the contiguous atomic-accumulator slots (256 KiB)
  hipMemsetAsync(slots1, 0, (size_t)(64*128*2 + 64*128*2 + 64*256*2)*4, stream);

  transpose_kernel<<<dim3(128,4,8), 256, 0, stream>>>(features, featT);
  wprep_kernel<<<64, 256, 0, stream>>>(W1, W2, W3, Wt1, Wt2, Wt3);
  fps_kernel<<<8, 256, 0, stream>>>(xyz, out, nxyz);
  qbp_kernel<<<2048, 256, 0, stream>>>(xyz, nxyz, gi);

  const float inv_cnt = 1.0f / (float)M_;
  mm_fused<1><<<4096, 256, 0, stream>>>(featT, Wt1, Wt2, Wt3, gi, xyz, nxyz,
                                        nullptr, nullptr, slots1, nullptr, nullptr);
  stats_kernel<<<1, 128, 0, stream>>>(slots1, g1, b1, ss1, 128, inv_cnt);
  mm_fused<2><<<4096, 256, 0, stream>>>(featT, Wt1, Wt2, Wt3, gi, xyz, nxyz,
                                        ss1, nullptr, slots2, nullptr, nullptr);
  stats_kernel<<<1, 128, 0, stream>>>(slots2, g2, b2, ss2, 128, inv_cnt);
  mm_fused<3><<<4096, 256, 0, stream>>>(featT, Wt1, Wt2, Wt3, gi, xyz, nxyz,
                                        ss1, ss2, slots3, minv, maxv);
  stats_kernel<<<1, 256, 0, stream>>>(slots3, g3, b3, ss3, 256, inv_cnt);
  final_kernel<<<dim3(4,16,8), 256, 0, stream>>>(minv, maxv, ss3, out + 24576);
}

// Round 5
// 1453.331 us; speedup vs baseline: 1.0616x; 1.0616x over previous
//
#include <hip/hip_runtime.h>

#define B_  8
#define N_  4096
#define S_  1024
#define K_  64
#define CF_ 128
#define M_  (B_*S_*K_)   // 524288 rows per layer

typedef __attribute__((ext_vector_type(8))) short bshort8;
typedef __attribute__((ext_vector_type(4))) float f32x4;

__device__ __forceinline__ unsigned short f2bf(float f){
  unsigned int u = __float_as_uint(f);
  u = u + 0x7FFFu + ((u >> 16) & 1u);      // RTNE
  return (unsigned short)(u >> 16);
}
__device__ __forceinline__ float bf2f(unsigned short h){
  return __uint_as_float(((unsigned int)h) << 16);
}

// ---------------------------------------------------------------------------
// FPS v2: one block (512 thr) per batch. Distance math BITWISE-FROZEN
// (verified passing rounds 2-4): d=((dx*dx)+(dy*dy))+(dz*dz) plain rn ops,
// fminf accumulate, argmax first-index tie-break.
// v2 structure: no global stores in loop (no vmcnt drain before s_barrier),
// ONE barrier/iter (double-buffered wave slots), DPP wave64 pair-reduce
// (xor1,xor2,ror4,ror8,bcast15,bcast31 -> lane63 holds wave result).
// Lex-max combine (val desc, idx asc) is associative+commutative, so any
// full-coverage tree preserves np.argmax first-occurrence semantics.
// ---------------------------------------------------------------------------
#define DPP_PAIR_STEP(CTRL)                                                     \
  {                                                                             \
    int _vi = __builtin_amdgcn_update_dpp(__float_as_int(best), __float_as_int(best), (CTRL), 0xF, 0xF, false); \
    int _ii = __builtin_amdgcn_update_dpp(bidx, bidx, (CTRL), 0xF, 0xF, false); \
    float _ov = __int_as_float(_vi);                                            \
    bool _tk = (_ov > best) || (_ov == best && _ii < bidx);                     \
    best = _tk ? _ov : best;                                                    \
    bidx = _tk ? _ii : bidx;                                                    \
  }

__global__ __launch_bounds__(512) void fps_kernel(const float* __restrict__ xyz,
                                                  float* __restrict__ nx_out,
                                                  float* __restrict__ nx_ws){
  __shared__ float sx[N_], sy[N_], sz[N_];
  __shared__ int   sidx[S_];
  __shared__ float wvv[2][8];
  __shared__ int   wvi[2][8];
  const int b = blockIdx.x, t = threadIdx.x;
  const int lane = t & 63, w = t >> 6;
  const float* xb = xyz + (size_t)b*N_*3;
  float px[8], py[8], pz[8], dist[8];
  int   idxc[8];
#pragma unroll
  for (int j=0;j<8;++j){
    int i = j*512 + t;
    px[j] = xb[i*3+0]; py[j] = xb[i*3+1]; pz[j] = xb[i*3+2];
    dist[j] = 1e10f;
    idxc[j] = i;
    sx[i]=px[j]; sy[i]=py[j]; sz[i]=pz[j];
  }
  __syncthreads();
  int farthest = 0;
  for (int it=0; it<S_; ++it){
    if (t==0) sidx[it] = farthest;
    float cx = sx[farthest], cy = sy[farthest], cz = sz[farthest];
    float best = -1.0f; int bidx = 0;
#pragma unroll
    for (int j=0;j<8;++j){
      float dx = __fsub_rn(px[j],cx), dy = __fsub_rn(py[j],cy), dz = __fsub_rn(pz[j],cz);
      float d  = __fadd_rn(__fadd_rn(__fmul_rn(dx,dx),__fmul_rn(dy,dy)),__fmul_rn(dz,dz));
      float nd = fminf(dist[j], d);
      dist[j] = nd;
      bool tk = nd > best;
      best = tk ? nd : best;
      bidx = tk ? idxc[j] : bidx;
    }
    // wave64 pair-reduce via DPP; lane 63 ends with the wave result
    DPP_PAIR_STEP(0xB1);   // quad_perm [1,0,3,2]  (xor 1)
    DPP_PAIR_STEP(0x4E);   // quad_perm [2,3,0,1]  (xor 2)
    DPP_PAIR_STEP(0x124);  // row_ror:4
    DPP_PAIR_STEP(0x128);  // row_ror:8
    DPP_PAIR_STEP(0x142);  // row_bcast:15
    DPP_PAIR_STEP(0x143);  // row_bcast:31
    const int buf = it & 1;
    if (lane == 63){ wvv[buf][w] = best; wvi[buf][w] = bidx; }
    __syncthreads();
    float bv = wvv[buf][0]; int bi = wvi[buf][0];
#pragma unroll
    for (int w2=1; w2<8; ++w2){
      float ov = wvv[buf][w2]; int oi = wvi[buf][w2];
      bool tk = (ov > bv) || (ov == bv && oi < bi);
      bv = tk ? ov : bv;
      bi = tk ? oi : bi;
    }
    farthest = bi;
  }
  __syncthreads();
  // write the 1024 selected centroids once, at the end
  for (int i=t; i<S_; i+=512){
    int id = sidx[i];
    size_t base = (size_t)(b*S_+i)*3;
    float vx=sx[id], vy=sy[id], vz=sz[id];
    nx_out[base+0]=vx; nx_out[base+1]=vy; nx_out[base+2]=vz;
    nx_ws[base+0]=vx;  nx_ws[base+1]=vy;  nx_ws[base+2]=vz;
  }
}

// ---------------------------------------------------------------------------
// Ball query: one wave per (b,s); ascending first-64 indices, pad with first.
// f64 membership (golden np ref evaluates in float64) — VERIFIED round 4.
// ---------------------------------------------------------------------------
__global__ __launch_bounds__(256) void qbp_kernel(const float* __restrict__ xyz,
                                                  const float* __restrict__ nx,
                                                  int* __restrict__ gi){
  const double R2 = 0.2*0.2;   // 0.04000000000000001 (f64)
  int gtid = blockIdx.x*256 + threadIdx.x;
  int wid = gtid >> 6, lane = gtid & 63;
  int b = wid >> 10, s = wid & 1023;
  const float* xb = xyz + (size_t)b*N_*3;
  const float* c  = nx + (size_t)(b*S_+s)*3;
  double cx=(double)c[0], cy=(double)c[1], cz=(double)c[2];
  double cc = cx*cx + cy*cy + cz*cz;
  int* g = gi + (size_t)(b*S_+s)*K_;
  int count = 0, first = -1;
  for (int ch=0; ch<64 && count<K_; ++ch){
    int i = ch*64 + lane;
    double x = (double)xb[i*3+0], y = (double)xb[i*3+1], z = (double)xb[i*3+2];
    double e  = cx*x + cy*y + cz*z;
    double pp = x*x + y*y + z*z;
    double d  = -2.0*e + cc + pp;
    bool keep = !(d > R2);
    unsigned long long bal = __ballot(keep);
    int pos = count + __builtin_popcountll(bal & ((1ull<<lane)-1ull));
    if (keep && pos < K_) g[pos] = i;
    if (first < 0 && bal) first = ch*64 + (int)__builtin_ctzll(bal);
    count += __builtin_popcountll(bal);
  }
  if (count < K_){
    int p = count + lane;
    if (p < K_) g[p] = first;
  }
}

// ---------------------------------------------------------------------------
// features (B,128,4096) f32 -> featT (B,4096,128) bf16
// ---------------------------------------------------------------------------
__global__ __launch_bounds__(256) void transpose_kernel(const float* __restrict__ f,
                                                        unsigned short* __restrict__ ft){
  __shared__ float tile[32][33];
  int b = blockIdx.z, ct = blockIdx.y, nt = blockIdx.x;
  int tx = threadIdx.x & 31, ty = threadIdx.x >> 5;
#pragma unroll
  for (int r=0; r<32; r+=8)
    tile[ty+r][tx] = f[((size_t)(b*128 + ct*32 + ty + r))*4096 + nt*32 + tx];
  __syncthreads();
#pragma unroll
  for (int r=0; r<32; r+=8){
    int n = nt*32 + ty + r, cc = ct*32 + tx;
    ft[((size_t)b*4096 + n)*128 + cc] = f2bf(tile[tx][ty+r]);
  }
}

// ---------------------------------------------------------------------------
// Weights -> bf16 [n][k]; layer-1 K permuted to [feat(0..127), dxyz(128..130), 0-pad..159]
// ---------------------------------------------------------------------------
__global__ void wprep_kernel(const float* __restrict__ W1, const float* __restrict__ W2,
                             const float* __restrict__ W3,
                             unsigned short* __restrict__ Wt1, unsigned short* __restrict__ Wt2,
                             unsigned short* __restrict__ Wt3){
  int t = blockIdx.x*blockDim.x + threadIdx.x;
  int stride = gridDim.x*blockDim.x;
  for (int idx=t; idx<128*160; idx+=stride){
    int n = idx/160, k = idx-(idx/160)*160;
    float v = 0.f;
    if (k < 128) v = W1[(k+3)*128 + n];
    else if (k < 131) v = W1[(k-128)*128 + n];
    Wt1[idx] = f2bf(v);
  }
  for (int idx=t; idx<128*128; idx+=stride){
    int n = idx>>7, k = idx&127;
    Wt2[idx] = f2bf(W2[k*128+n]);
  }
  for (int idx=t; idx<256*128; idx+=stride){
    int n = idx>>7, k = idx&127;
    Wt3[idx] = f2bf(W3[k*256+n]);
  }
}

// ---------------------------------------------------------------------------
// Fused recompute GEMM chain per 128-row slab. No y1/y2 in global memory.
// PHASE 1: GEMM1 -> col sums1
// PHASE 2: GEMM1 -> BN1+ReLU(LDS) -> GEMM2 -> col sums2
// PHASE 3: GEMM1 -> BN1 -> GEMM2 -> BN2 -> GEMM3 (2 N-halves) -> sums3 + min/max over K
// ---------------------------------------------------------------------------
template<int PHASE>
__global__ __launch_bounds__(256,2) void mm_fused(
    const unsigned short* __restrict__ featT,
    const unsigned short* __restrict__ Wt1,
    const unsigned short* __restrict__ Wt2,
    const unsigned short* __restrict__ Wt3,
    const int* __restrict__ gi,
    const float* __restrict__ xyz,
    const float* __restrict__ nxyz,
    const float* __restrict__ ss1,
    const float* __restrict__ ss2,
    float* __restrict__ slots,
    float* __restrict__ minv,
    float* __restrict__ maxv)
{
  __shared__ alignas(16) unsigned short At[128*40];
  __shared__ alignas(16) unsigned short Bt[128*40];
  __shared__ alignas(16) unsigned short Y[(PHASE>=2)?(128*136):16];
  __shared__ int giL[128];

  const int t = threadIdx.x;
  const int mblk = blockIdx.x;
  const int b = mblk >> 9;                 // 512 slabs per batch
  const int lane = t&63, wave = t>>6;
  const int wm = wave>>1, wn = wave&1;
  const int lrow = lane&15, quad = lane>>4;
  const int slot = mblk & 63;

  if (t<128) giL[t] = gi[(size_t)mblk*128 + t];
  __syncthreads();

  f32x4 acc[4][4];
  const f32x4 z4 = {0.f,0.f,0.f,0.f};
#pragma unroll
  for (int i=0;i<4;++i)
#pragma unroll
    for (int j=0;j<4;++j) acc[i][j]=z4;

  // ---------------- GEMM1: A = gathered [feat | dxyz | pad], K=160 ----------
  for (int ch=0; ch<5; ++ch){
#pragma unroll
    for (int half=0; half<2; ++half){
      int sl = t + half*256; int r = sl>>2, p = sl&3;
      *(bshort8*)&Bt[r*40+p*8] = *(const bshort8*)(Wt1 + r*160 + ch*32 + p*8);
      if (ch < 4){
        int i = giL[r];
        *(bshort8*)&At[r*40+p*8] =
            *(const bshort8*)(featT + ((size_t)b*N_ + i)*CF_ + ch*32 + p*8);
      } else {
        union { bshort8 v; unsigned short u[8]; } o;
#pragma unroll
        for (int e=0;e<8;++e) o.u[e]=0;
        if (p==0){
          int i = giL[r];
          int s = ((mblk*128 + r) >> 6) & 1023;
          const float* pp = xyz  + ((size_t)b*N_ + i)*3;
          const float* qq = nxyz + (size_t)(b*S_ + s)*3;
          o.u[0] = f2bf(__fsub_rn(pp[0],qq[0]));
          o.u[1] = f2bf(__fsub_rn(pp[1],qq[1]));
          o.u[2] = f2bf(__fsub_rn(pp[2],qq[2]));
        }
        *(bshort8*)&At[r*40+p*8] = o.v;
      }
    }
    __syncthreads();
    bshort8 af[4], bfr[4];
#pragma unroll
    for (int mt=0; mt<4; ++mt) af[mt]  = *(const bshort8*)&At[(wm*64+mt*16+lrow)*40 + quad*8];
#pragma unroll
    for (int nt=0; nt<4; ++nt) bfr[nt] = *(const bshort8*)&Bt[(wn*64+nt*16+lrow)*40 + quad*8];
#pragma unroll
    for (int mt=0; mt<4; ++mt)
#pragma unroll
      for (int nt=0; nt<4; ++nt)
        acc[mt][nt] = __builtin_amdgcn_mfma_f32_16x16x32_bf16(af[mt], bfr[nt], acc[mt][nt], 0,0,0);
    __syncthreads();
  }

  if constexpr (PHASE==1){
#pragma unroll
    for (int nt=0; nt<4; ++nt){
      float s=0.f, s2=0.f;
#pragma unroll
      for (int mt=0; mt<4; ++mt)
#pragma unroll
        for (int r=0; r<4; ++r){ float v=acc[mt][nt][r]; s+=v; s2=fmaf(v,v,s2); }
      s  += __shfl_xor(s,16,64);  s  += __shfl_xor(s,32,64);
      s2 += __shfl_xor(s2,16,64); s2 += __shfl_xor(s2,32,64);
      if (lane<16){
        int c = wn*64+nt*16+lane;
        atomicAdd(&slots[(slot*128+c)*2+0], s);
        atomicAdd(&slots[(slot*128+c)*2+1], s2);
      }
    }
    return;
  }

  if constexpr (PHASE>=2){
    // ---- BN1 + ReLU -> Y (C-layout: col=lane&15, row=quad*4+reg) ----
#pragma unroll
    for (int nt=0; nt<4; ++nt){
      int c = wn*64+nt*16+lrow;
      float sc = ss1[c], sh = ss1[128+c];
#pragma unroll
      for (int mt=0; mt<4; ++mt)
#pragma unroll
        for (int r=0; r<4; ++r){
          int row = wm*64+mt*16+quad*4+r;
          Y[row*136 + c] = f2bf(fmaxf(fmaf(acc[mt][nt][r], sc, sh), 0.f));
        }
    }
    __syncthreads();

    // ---------------- GEMM2: A = Y (z1), K=128 ----------------
#pragma unroll
    for (int i=0;i<4;++i)
#pragma unroll
      for (int j=0;j<4;++j) acc[i][j]=z4;
    for (int ch=0; ch<4; ++ch){
#pragma unroll
      for (int half=0; half<2; ++half){
        int sl = t + half*256; int r = sl>>2, p = sl&3;
        *(bshort8*)&Bt[r*40+p*8] = *(const bshort8*)(Wt2 + r*128 + ch*32 + p*8);
      }
      __syncthreads();
      bshort8 af[4], bfr[4];
#pragma unroll
      for (int mt=0; mt<4; ++mt) af[mt]  = *(const bshort8*)&Y[(wm*64+mt*16+lrow)*136 + ch*32 + quad*8];
#pragma unroll
      for (int nt=0; nt<4; ++nt) bfr[nt] = *(const bshort8*)&Bt[(wn*64+nt*16+lrow)*40 + quad*8];
#pragma unroll
      for (int mt=0; mt<4; ++mt)
#pragma unroll
        for (int nt=0; nt<4; ++nt)
          acc[mt][nt] = __builtin_amdgcn_mfma_f32_16x16x32_bf16(af[mt], bfr[nt], acc[mt][nt], 0,0,0);
      __syncthreads();
    }
  }

  if constexpr (PHASE==2){
#pragma unroll
    for (int nt=0; nt<4; ++nt){
      float s=0.f, s2=0.f;
#pragma unroll
      for (int mt=0; mt<4; ++mt)
#pragma unroll
        for (int r=0; r<4; ++r){ float v=acc[mt][nt][r]; s+=v; s2=fmaf(v,v,s2); }
      s  += __shfl_xor(s,16,64);  s  += __shfl_xor(s,32,64);
      s2 += __shfl_xor(s2,16,64); s2 += __shfl_xor(s2,32,64);
      if (lane<16){
        int c = wn*64+nt*16+lane;
        atomicAdd(&slots[(slot*128+c)*2+0], s);
        atomicAdd(&slots[(slot*128+c)*2+1], s2);
      }
    }
    return;
  }

  if constexpr (PHASE==3){
    // ---- BN2 + ReLU -> Y (overwrite) ----
#pragma unroll
    for (int nt=0; nt<4; ++nt){
      int c = wn*64+nt*16+lrow;
      float sc = ss2[c], sh = ss2[128+c];
#pragma unroll
      for (int mt=0; mt<4; ++mt)
#pragma unroll
        for (int r=0; r<4; ++r){
          int row = wm*64+mt*16+quad*4+r;
          Y[row*136 + c] = f2bf(fmaxf(fmaf(acc[mt][nt][r], sc, sh), 0.f));
        }
    }
    __syncthreads();

    // ---------------- GEMM3: A = Y (z2), Nout=256 in two halves ------------
    for (int h=0; h<2; ++h){
#pragma unroll
      for (int i=0;i<4;++i)
#pragma unroll
        for (int j=0;j<4;++j) acc[i][j]=z4;
      for (int ch=0; ch<4; ++ch){
#pragma unroll
        for (int half=0; half<2; ++half){
          int sl = t + half*256; int r = sl>>2, p = sl&3;
          *(bshort8*)&Bt[r*40+p*8] =
              *(const bshort8*)(Wt3 + ((size_t)(h*128+r))*128 + ch*32 + p*8);
        }
        __syncthreads();
        bshort8 af[4], bfr[4];
#pragma unroll
        for (int mt=0; mt<4; ++mt) af[mt]  = *(const bshort8*)&Y[(wm*64+mt*16+lrow)*136 + ch*32 + quad*8];
#pragma unroll
        for (int nt=0; nt<4; ++nt) bfr[nt] = *(const bshort8*)&Bt[(wn*64+nt*16+lrow)*40 + quad*8];
#pragma unroll
        for (int mt=0; mt<4; ++mt)
#pragma unroll
          for (int nt=0; nt<4; ++nt)
            acc[mt][nt] = __builtin_amdgcn_mfma_f32_16x16x32_bf16(af[mt], bfr[nt], acc[mt][nt], 0,0,0);
        __syncthreads();
      }
      // epilogue: sums3 + per-(b,s) min/max over the 64 rows of each group
#pragma unroll
      for (int nt=0; nt<4; ++nt){
        float s=0.f, s2=0.f, mx=-3.0e38f, mn=3.0e38f;
#pragma unroll
        for (int mt=0; mt<4; ++mt)
#pragma unroll
          for (int r=0; r<4; ++r){
            float v=acc[mt][nt][r];
            s+=v; s2=fmaf(v,v,s2);
            mx=fmaxf(mx,v); mn=fminf(mn,v);
          }
        s  += __shfl_xor(s,16,64);  s  += __shfl_xor(s,32,64);
        s2 += __shfl_xor(s2,16,64); s2 += __shfl_xor(s2,32,64);
        mx = fmaxf(mx, __shfl_xor(mx,16,64)); mx = fmaxf(mx, __shfl_xor(mx,32,64));
        mn = fminf(mn, __shfl_xor(mn,16,64)); mn = fminf(mn, __shfl_xor(mn,32,64));
        if (lane<16){
          int c = h*128 + wn*64+nt*16+lane;
          atomicAdd(&slots[(slot*256+c)*2+0], s);
          atomicAdd(&slots[(slot*256+c)*2+1], s2);
          size_t sidx = (size_t)mblk*2 + wm;         // global (b*1024+s)
          maxv[sidx*256 + c] = mx;
          minv[sidx*256 + c] = mn;
        }
      }
    }
  }
}

// ---------------------------------------------------------------------------
// Reduce 64 partial-sum slots -> per-channel scale/shift
// ---------------------------------------------------------------------------
__global__ void stats_kernel(const float* __restrict__ slots, const float* __restrict__ g,
                             const float* __restrict__ beta, float* __restrict__ ssOut,
                             int C, float inv_cnt){
  int c = threadIdx.x;
  if (c >= C) return;
  float s=0.f, s2=0.f;
  for (int k=0;k<64;++k){
    s  += slots[(k*C + c)*2 + 0];
    s2 += slots[(k*C + c)*2 + 1];
  }
  float m = s * inv_cnt;
  float v = fmaxf(s2 * inv_cnt - m*m, 0.f);
  float sc = rsqrtf(v + 1e-5f) * g[c];
  ssOut[c] = sc;
  ssOut[C + c] = beta[c] - m*sc;
}

// ---------------------------------------------------------------------------
// BN3 affine + relu on per-group max (min if scale<0); LDS-transposed so both
// the min/max reads and the (b,c,s)-layout writes are coalesced.
// ---------------------------------------------------------------------------
__global__ __launch_bounds__(256) void final_kernel(const float* __restrict__ minv,
                                                    const float* __restrict__ maxv,
                                                    const float* __restrict__ ss3,
                                                    float* __restrict__ out){
  __shared__ float tile[64][65];
  const int t = threadIdx.x;
  const int cb = blockIdx.x;   // 0..3  (64-channel block)
  const int sb = blockIdx.y;   // 0..15 (64-sample block)
  const int b  = blockIdx.z;   // 0..7
  const int w = t>>6, l = t&63;
  {
    int c = cb*64 + l;
    float sc = ss3[c], sh = ss3[256+c];
#pragma unroll
    for (int k=0;k<16;++k){
      int sl = k*4 + w;
      size_t mi = ((size_t)(b*1024 + sb*64 + sl))*256 + c;
      float v = (sc >= 0.f) ? maxv[mi] : minv[mi];
      tile[sl][l] = fmaxf(fmaf(v, sc, sh), 0.f);
    }
  }
  __syncthreads();
#pragma unroll
  for (int k=0;k<16;++k){
    int cl = k*4 + w;
    out[((size_t)(b*256 + cb*64 + cl))*1024 + sb*64 + l] = tile[l][cl];
  }
}

// ---------------------------------------------------------------------------
extern "C" void kernel_launch(void* const* d_in, const int* in_sizes, int n_in,
                              void* d_out, int out_size, void* d_ws, size_t ws_size,
                              hipStream_t stream){
  const float* xyz      = (const float*)d_in[0];
  const float* features = (const float*)d_in[1];
  const float* W1 = (const float*)d_in[2];
  const float* g1 = (const float*)d_in[3];
  const float* b1 = (const float*)d_in[4];
  const float* W2 = (const float*)d_in[5];
  const float* g2 = (const float*)d_in[6];
  const float* b2 = (const float*)d_in[7];
  const float* W3 = (const float*)d_in[8];
  const float* g3 = (const float*)d_in[9];
  const float* b3 = (const float*)d_in[10];
  float* out = (float*)d_out;

  char* ws = (char*)d_ws;
  size_t off = 0;
  auto alloc = [&](size_t bytes)->char*{
    char* p = ws + off;
    off = (off + bytes + 255) & ~(size_t)255;
    return p;
  };
  // total ~28 MB
  float* slots1 = (float*)alloc((size_t)64*128*2*4);
  float* slots2 = (float*)alloc((size_t)64*128*2*4);
  float* slots3 = (float*)alloc((size_t)64*256*2*4);
  float* ss1    = (float*)alloc(256*4);
  float* ss2    = (float*)alloc(256*4);
  float* ss3    = (float*)alloc(512*4);
  float* nxyz   = (float*)alloc((size_t)24576*4);
  int*   gi     = (int*)  alloc((size_t)M_*4);
  unsigned short* featT = (unsigned short*)alloc((size_t)B_*N_*CF_*2);
  unsigned short* Wt1   = (unsigned short*)alloc((size_t)128*160*2);
  unsigned short* Wt2   = (unsigned short*)alloc((size_t)128*128*2);
  unsigned short* Wt3   = (unsigned short*)alloc((size_t)256*128*2);
  float* minv = (float*)alloc((size_t)B_*S_*256*4);
  float* maxv = (float*)alloc((size_t)B_*S_*256*4);

  // zero the contiguous atomic-accumulator slots (256 KiB)
  hipMemsetAsync(slots1, 0, (size_t)(64*128*2 + 64*128*2 + 64*256*2)*4, stream);

  transpose_kernel<<<dim3(128,4,8), 256, 0, stream>>>(features, featT);
  wprep_kernel<<<64, 256, 0, stream>>>(W1, W2, W3, Wt1, Wt2, Wt3);
  fps_kernel<<<8, 512, 0, stream>>>(xyz, out, nxyz);
  qbp_kernel<<<2048, 256, 0, stream>>>(xyz, nxyz, gi);

  const float inv_cnt = 1.0f / (float)M_;
  mm_fused<1><<<4096, 256, 0, stream>>>(featT, Wt1, Wt2, Wt3, gi, xyz, nxyz,
                                        nullptr, nullptr, slots1, nullptr, nullptr);
  stats_kernel<<<1, 128, 0, stream>>>(slots1, g1, b1, ss1, 128, inv_cnt);
  mm_fused<2><<<4096, 256, 0, stream>>>(featT, Wt1, Wt2, Wt3, gi, xyz, nxyz,
                                        ss1, nullptr, slots2, nullptr, nullptr);
  stats_kernel<<<1, 128, 0, stream>>>(slots2, g2, b2, ss2, 128, inv_cnt);
  mm_fused<3><<<4096, 256, 0, stream>>>(featT, Wt1, Wt2, Wt3, gi, xyz, nxyz,
                                        ss1, ss2, slots3, minv, maxv);
  stats_kernel<<<1, 256, 0, stream>>>(slots3, g3, b3, ss3, 256, inv_cnt);
  final_kernel<<<dim3(4,16,8), 256, 0, stream>>>(minv, maxv, ss3, out + 24576);
}

// Round 6
// 1172.124 us; speedup vs baseline: 1.3163x; 1.2399x over previous
//
#include <hip/hip_runtime.h>

#define B_  8
#define N_  4096
#define S_  1024
#define K_  64
#define CF_ 128
#define M_  (B_*S_*K_)   // 524288 rows per layer

typedef __attribute__((ext_vector_type(8))) short bshort8;
typedef __attribute__((ext_vector_type(4))) float f32x4;
typedef __attribute__((ext_vector_type(4))) int   i32x4;

__device__ __forceinline__ unsigned short f2bf(float f){
  unsigned int u = __float_as_uint(f);
  u = u + 0x7FFFu + ((u >> 16) & 1u);      // RTNE
  return (unsigned short)(u >> 16);
}
__device__ __forceinline__ float bf2f(unsigned short h){
  return __uint_as_float(((unsigned int)h) << 16);
}

// ---------------------------------------------------------------------------
// FPS v3: one block (256 thr = 4 waves, 1/SIMD) per batch.
// Distance math BITWISE-FROZEN (verified passing rounds 2-5): plain rn ops,
// fminf accumulate, strict-> argmax with first-index tie-break, i = j*256+t.
// v3: single barrier/iter, DPP wave64 pair-reduce (verified r5), 4 wave
// slots packed for b128 combine reads, tree lex-max combine (associative ->
// preserves np.argmax first-occurrence), no global stores in loop.
// ---------------------------------------------------------------------------
#define DPP_PAIR_STEP(CTRL)                                                     \
  {                                                                             \
    int _vi = __builtin_amdgcn_update_dpp(__float_as_int(best), __float_as_int(best), (CTRL), 0xF, 0xF, false); \
    int _ii = __builtin_amdgcn_update_dpp(bidx, bidx, (CTRL), 0xF, 0xF, false); \
    float _ov = __int_as_float(_vi);                                            \
    bool _tk = (_ov > best) || (_ov == best && _ii < bidx);                     \
    best = _tk ? _ov : best;                                                    \
    bidx = _tk ? _ii : bidx;                                                    \
  }

__global__ __launch_bounds__(256) void fps_kernel(const float* __restrict__ xyz,
                                                  float* __restrict__ nx_out,
                                                  float* __restrict__ nx_ws){
  __shared__ float sx[N_], sy[N_], sz[N_];
  __shared__ int   sidx[S_];
  __shared__ alignas(16) float redv[2][4];
  __shared__ alignas(16) int   redi[2][4];
  const int b = blockIdx.x, t = threadIdx.x;
  const int lane = t & 63, w = t >> 6;      // 4 waves
  const float* xb = xyz + (size_t)b*N_*3;
  float px[16], py[16], pz[16], dist[16];
#pragma unroll
  for (int j=0;j<16;++j){
    int i = j*256 + t;
    px[j] = xb[i*3+0]; py[j] = xb[i*3+1]; pz[j] = xb[i*3+2];
    dist[j] = 1e10f;
    sx[i]=px[j]; sy[i]=py[j]; sz[i]=pz[j];
  }
  __syncthreads();
  int farthest = 0;
  for (int it=0; it<S_; ++it){
    if (t==0) sidx[it] = farthest;
    float cx = sx[farthest], cy = sy[farthest], cz = sz[farthest];
    float best = -1.0f; int bidx = 0;
#pragma unroll
    for (int j=0;j<16;++j){
      float dx = __fsub_rn(px[j],cx), dy = __fsub_rn(py[j],cy), dz = __fsub_rn(pz[j],cz);
      float d  = __fadd_rn(__fadd_rn(__fmul_rn(dx,dx),__fmul_rn(dy,dy)),__fmul_rn(dz,dz));
      float nd = fminf(dist[j], d);
      dist[j] = nd;
      bool tk = nd > best;
      best = tk ? nd : best;
      bidx = tk ? (j*256 + t) : bidx;
    }
    // wave64 pair-reduce via DPP; lane 63 ends with the wave result
    DPP_PAIR_STEP(0xB1);   // quad_perm [1,0,3,2]  (xor 1)
    DPP_PAIR_STEP(0x4E);   // quad_perm [2,3,0,1]  (xor 2)
    DPP_PAIR_STEP(0x124);  // row_ror:4
    DPP_PAIR_STEP(0x128);  // row_ror:8
    DPP_PAIR_STEP(0x142);  // row_bcast:15
    DPP_PAIR_STEP(0x143);  // row_bcast:31
    const int buf = it & 1;
    if (lane == 63){ redv[buf][w] = best; redi[buf][w] = bidx; }
    __syncthreads();
    f32x4 vv = *(const f32x4*)&redv[buf][0];   // one ds_read_b128
    i32x4 iv = *(const i32x4*)&redi[buf][0];   // one ds_read_b128
    // tree lex-max combine (associative; first-index tie-break preserved)
    float v01 = vv[0]; int i01 = iv[0];
    { bool tk = (vv[1] > v01) || (vv[1] == v01 && iv[1] < i01); v01 = tk?vv[1]:v01; i01 = tk?iv[1]:i01; }
    float v23 = vv[2]; int i23 = iv[2];
    { bool tk = (vv[3] > v23) || (vv[3] == v23 && iv[3] < i23); v23 = tk?vv[3]:v23; i23 = tk?iv[3]:i23; }
    { bool tk = (v23 > v01) || (v23 == v01 && i23 < i01); v01 = tk?v23:v01; i01 = tk?i23:i01; }
    farthest = i01;
  }
  __syncthreads();
  // write the 1024 selected centroids once, at the end
  for (int i=t; i<S_; i+=256){
    int id = sidx[i];
    size_t base = (size_t)(b*S_+i)*3;
    float vx=sx[id], vy=sy[id], vz=sz[id];
    nx_out[base+0]=vx; nx_out[base+1]=vy; nx_out[base+2]=vz;
    nx_ws[base+0]=vx;  nx_ws[base+1]=vy;  nx_ws[base+2]=vz;
  }
}

// ---------------------------------------------------------------------------
// Ball query: one wave per (b,s); ascending first-64 indices, pad with first.
// f64 membership (golden np ref evaluates in float64) — VERIFIED round 4.
// ---------------------------------------------------------------------------
__global__ __launch_bounds__(256) void qbp_kernel(const float* __restrict__ xyz,
                                                  const float* __restrict__ nx,
                                                  int* __restrict__ gi){
  const double R2 = 0.2*0.2;   // 0.04000000000000001 (f64)
  int gtid = blockIdx.x*256 + threadIdx.x;
  int wid = gtid >> 6, lane = gtid & 63;
  int b = wid >> 10, s = wid & 1023;
  const float* xb = xyz + (size_t)b*N_*3;
  const float* c  = nx + (size_t)(b*S_+s)*3;
  double cx=(double)c[0], cy=(double)c[1], cz=(double)c[2];
  double cc = cx*cx + cy*cy + cz*cz;
  int* g = gi + (size_t)(b*S_+s)*K_;
  int count = 0, first = -1;
  for (int ch=0; ch<64 && count<K_; ++ch){
    int i = ch*64 + lane;
    double x = (double)xb[i*3+0], y = (double)xb[i*3+1], z = (double)xb[i*3+2];
    double e  = cx*x + cy*y + cz*z;
    double pp = x*x + y*y + z*z;
    double d  = -2.0*e + cc + pp;
    bool keep = !(d > R2);
    unsigned long long bal = __ballot(keep);
    int pos = count + __builtin_popcountll(bal & ((1ull<<lane)-1ull));
    if (keep && pos < K_) g[pos] = i;
    if (first < 0 && bal) first = ch*64 + (int)__builtin_ctzll(bal);
    count += __builtin_popcountll(bal);
  }
  if (count < K_){
    int p = count + lane;
    if (p < K_) g[p] = first;
  }
}

// ---------------------------------------------------------------------------
// features (B,128,4096) f32 -> featT (B,4096,128) bf16
// ---------------------------------------------------------------------------
__global__ __launch_bounds__(256) void transpose_kernel(const float* __restrict__ f,
                                                        unsigned short* __restrict__ ft){
  __shared__ float tile[32][33];
  int b = blockIdx.z, ct = blockIdx.y, nt = blockIdx.x;
  int tx = threadIdx.x & 31, ty = threadIdx.x >> 5;
#pragma unroll
  for (int r=0; r<32; r+=8)
    tile[ty+r][tx] = f[((size_t)(b*128 + ct*32 + ty + r))*4096 + nt*32 + tx];
  __syncthreads();
#pragma unroll
  for (int r=0; r<32; r+=8){
    int n = nt*32 + ty + r, cc = ct*32 + tx;
    ft[((size_t)b*4096 + n)*128 + cc] = f2bf(tile[tx][ty+r]);
  }
}

// ---------------------------------------------------------------------------
// Weights -> bf16 [n][k]; layer-1 K permuted to [feat(0..127), dxyz(128..130), 0-pad..159]
// ---------------------------------------------------------------------------
__global__ void wprep_kernel(const float* __restrict__ W1, const float* __restrict__ W2,
                             const float* __restrict__ W3,
                             unsigned short* __restrict__ Wt1, unsigned short* __restrict__ Wt2,
                             unsigned short* __restrict__ Wt3){
  int t = blockIdx.x*blockDim.x + threadIdx.x;
  int stride = gridDim.x*blockDim.x;
  for (int idx=t; idx<128*160; idx+=stride){
    int n = idx/160, k = idx-(idx/160)*160;
    float v = 0.f;
    if (k < 128) v = W1[(k+3)*128 + n];
    else if (k < 131) v = W1[(k-128)*128 + n];
    Wt1[idx] = f2bf(v);
  }
  for (int idx=t; idx<128*128; idx+=stride){
    int n = idx>>7, k = idx&127;
    Wt2[idx] = f2bf(W2[k*128+n]);
  }
  for (int idx=t; idx<256*128; idx+=stride){
    int n = idx>>7, k = idx&127;
    Wt3[idx] = f2bf(W3[k*256+n]);
  }
}

// ---------------------------------------------------------------------------
// Fused recompute GEMM chain per 128-row slab. No y1/y2 in global memory.
// PHASE 1: GEMM1 -> col sums1
// PHASE 2: GEMM1 -> BN1+ReLU(LDS) -> GEMM2 -> col sums2
// PHASE 3: GEMM1 -> BN1 -> GEMM2 -> BN2 -> GEMM3 (2 N-halves) -> sums3 + min/max over K
// ---------------------------------------------------------------------------
template<int PHASE>
__global__ __launch_bounds__(256,2) void mm_fused(
    const unsigned short* __restrict__ featT,
    const unsigned short* __restrict__ Wt1,
    const unsigned short* __restrict__ Wt2,
    const unsigned short* __restrict__ Wt3,
    const int* __restrict__ gi,
    const float* __restrict__ xyz,
    const float* __restrict__ nxyz,
    const float* __restrict__ ss1,
    const float* __restrict__ ss2,
    float* __restrict__ slots,
    float* __restrict__ minv,
    float* __restrict__ maxv)
{
  __shared__ alignas(16) unsigned short At[128*40];
  __shared__ alignas(16) unsigned short Bt[128*40];
  __shared__ alignas(16) unsigned short Y[(PHASE>=2)?(128*136):16];
  __shared__ int giL[128];

  const int t = threadIdx.x;
  const int mblk = blockIdx.x;
  const int b = mblk >> 9;                 // 512 slabs per batch
  const int lane = t&63, wave = t>>6;
  const int wm = wave>>1, wn = wave&1;
  const int lrow = lane&15, quad = lane>>4;
  const int slot = mblk & 63;

  if (t<128) giL[t] = gi[(size_t)mblk*128 + t];
  __syncthreads();

  f32x4 acc[4][4];
  const f32x4 z4 = {0.f,0.f,0.f,0.f};
#pragma unroll
  for (int i=0;i<4;++i)
#pragma unroll
    for (int j=0;j<4;++j) acc[i][j]=z4;

  // ---------------- GEMM1: A = gathered [feat | dxyz | pad], K=160 ----------
  for (int ch=0; ch<5; ++ch){
#pragma unroll
    for (int half=0; half<2; ++half){
      int sl = t + half*256; int r = sl>>2, p = sl&3;
      *(bshort8*)&Bt[r*40+p*8] = *(const bshort8*)(Wt1 + r*160 + ch*32 + p*8);
      if (ch < 4){
        int i = giL[r];
        *(bshort8*)&At[r*40+p*8] =
            *(const bshort8*)(featT + ((size_t)b*N_ + i)*CF_ + ch*32 + p*8);
      } else {
        union { bshort8 v; unsigned short u[8]; } o;
#pragma unroll
        for (int e=0;e<8;++e) o.u[e]=0;
        if (p==0){
          int i = giL[r];
          int s = ((mblk*128 + r) >> 6) & 1023;
          const float* pp = xyz  + ((size_t)b*N_ + i)*3;
          const float* qq = nxyz + (size_t)(b*S_ + s)*3;
          o.u[0] = f2bf(__fsub_rn(pp[0],qq[0]));
          o.u[1] = f2bf(__fsub_rn(pp[1],qq[1]));
          o.u[2] = f2bf(__fsub_rn(pp[2],qq[2]));
        }
        *(bshort8*)&At[r*40+p*8] = o.v;
      }
    }
    __syncthreads();
    bshort8 af[4], bfr[4];
#pragma unroll
    for (int mt=0; mt<4; ++mt) af[mt]  = *(const bshort8*)&At[(wm*64+mt*16+lrow)*40 + quad*8];
#pragma unroll
    for (int nt=0; nt<4; ++nt) bfr[nt] = *(const bshort8*)&Bt[(wn*64+nt*16+lrow)*40 + quad*8];
#pragma unroll
    for (int mt=0; mt<4; ++mt)
#pragma unroll
      for (int nt=0; nt<4; ++nt)
        acc[mt][nt] = __builtin_amdgcn_mfma_f32_16x16x32_bf16(af[mt], bfr[nt], acc[mt][nt], 0,0,0);
    __syncthreads();
  }

  if constexpr (PHASE==1){
#pragma unroll
    for (int nt=0; nt<4; ++nt){
      float s=0.f, s2=0.f;
#pragma unroll
      for (int mt=0; mt<4; ++mt)
#pragma unroll
        for (int r=0; r<4; ++r){ float v=acc[mt][nt][r]; s+=v; s2=fmaf(v,v,s2); }
      s  += __shfl_xor(s,16,64);  s  += __shfl_xor(s,32,64);
      s2 += __shfl_xor(s2,16,64); s2 += __shfl_xor(s2,32,64);
      if (lane<16){
        int c = wn*64+nt*16+lane;
        atomicAdd(&slots[(slot*128+c)*2+0], s);
        atomicAdd(&slots[(slot*128+c)*2+1], s2);
      }
    }
    return;
  }

  if constexpr (PHASE>=2){
    // ---- BN1 + ReLU -> Y (C-layout: col=lane&15, row=quad*4+reg) ----
#pragma unroll
    for (int nt=0; nt<4; ++nt){
      int c = wn*64+nt*16+lrow;
      float sc = ss1[c], sh = ss1[128+c];
#pragma unroll
      for (int mt=0; mt<4; ++mt)
#pragma unroll
        for (int r=0; r<4; ++r){
          int row = wm*64+mt*16+quad*4+r;
          Y[row*136 + c] = f2bf(fmaxf(fmaf(acc[mt][nt][r], sc, sh), 0.f));
        }
    }
    __syncthreads();

    // ---------------- GEMM2: A = Y (z1), K=128 ----------------
#pragma unroll
    for (int i=0;i<4;++i)
#pragma unroll
      for (int j=0;j<4;++j) acc[i][j]=z4;
    for (int ch=0; ch<4; ++ch){
#pragma unroll
      for (int half=0; half<2; ++half){
        int sl = t + half*256; int r = sl>>2, p = sl&3;
        *(bshort8*)&Bt[r*40+p*8] = *(const bshort8*)(Wt2 + r*128 + ch*32 + p*8);
      }
      __syncthreads();
      bshort8 af[4], bfr[4];
#pragma unroll
      for (int mt=0; mt<4; ++mt) af[mt]  = *(const bshort8*)&Y[(wm*64+mt*16+lrow)*136 + ch*32 + quad*8];
#pragma unroll
      for (int nt=0; nt<4; ++nt) bfr[nt] = *(const bshort8*)&Bt[(wn*64+nt*16+lrow)*40 + quad*8];
#pragma unroll
      for (int mt=0; mt<4; ++mt)
#pragma unroll
        for (int nt=0; nt<4; ++nt)
          acc[mt][nt] = __builtin_amdgcn_mfma_f32_16x16x32_bf16(af[mt], bfr[nt], acc[mt][nt], 0,0,0);
      __syncthreads();
    }
  }

  if constexpr (PHASE==2){
#pragma unroll
    for (int nt=0; nt<4; ++nt){
      float s=0.f, s2=0.f;
#pragma unroll
      for (int mt=0; mt<4; ++mt)
#pragma unroll
        for (int r=0; r<4; ++r){ float v=acc[mt][nt][r]; s+=v; s2=fmaf(v,v,s2); }
      s  += __shfl_xor(s,16,64);  s  += __shfl_xor(s,32,64);
      s2 += __shfl_xor(s2,16,64); s2 += __shfl_xor(s2,32,64);
      if (lane<16){
        int c = wn*64+nt*16+lane;
        atomicAdd(&slots[(slot*128+c)*2+0], s);
        atomicAdd(&slots[(slot*128+c)*2+1], s2);
      }
    }
    return;
  }

  if constexpr (PHASE==3){
    // ---- BN2 + ReLU -> Y (overwrite) ----
#pragma unroll
    for (int nt=0; nt<4; ++nt){
      int c = wn*64+nt*16+lrow;
      float sc = ss2[c], sh = ss2[128+c];
#pragma unroll
      for (int mt=0; mt<4; ++mt)
#pragma unroll
        for (int r=0; r<4; ++r){
          int row = wm*64+mt*16+quad*4+r;
          Y[row*136 + c] = f2bf(fmaxf(fmaf(acc[mt][nt][r], sc, sh), 0.f));
        }
    }
    __syncthreads();

    // ---------------- GEMM3: A = Y (z2), Nout=256 in two halves ------------
    for (int h=0; h<2; ++h){
#pragma unroll
      for (int i=0;i<4;++i)
#pragma unroll
        for (int j=0;j<4;++j) acc[i][j]=z4;
      for (int ch=0; ch<4; ++ch){
#pragma unroll
        for (int half=0; half<2; ++half){
          int sl = t + half*256; int r = sl>>2, p = sl&3;
          *(bshort8*)&Bt[r*40+p*8] =
              *(const bshort8*)(Wt3 + ((size_t)(h*128+r))*128 + ch*32 + p*8);
        }
        __syncthreads();
        bshort8 af[4], bfr[4];
#pragma unroll
        for (int mt=0; mt<4; ++mt) af[mt]  = *(const bshort8*)&Y[(wm*64+mt*16+lrow)*136 + ch*32 + quad*8];
#pragma unroll
        for (int nt=0; nt<4; ++nt) bfr[nt] = *(const bshort8*)&Bt[(wn*64+nt*16+lrow)*40 + quad*8];
#pragma unroll
        for (int mt=0; mt<4; ++mt)
#pragma unroll
          for (int nt=0; nt<4; ++nt)
            acc[mt][nt] = __builtin_amdgcn_mfma_f32_16x16x32_bf16(af[mt], bfr[nt], acc[mt][nt], 0,0,0);
        __syncthreads();
      }
      // epilogue: sums3 + per-(b,s) min/max over the 64 rows of each group
#pragma unroll
      for (int nt=0; nt<4; ++nt){
        float s=0.f, s2=0.f, mx=-3.0e38f, mn=3.0e38f;
#pragma unroll
        for (int mt=0; mt<4; ++mt)
#pragma unroll
          for (int r=0; r<4; ++r){
            float v=acc[mt][nt][r];
            s+=v; s2=fmaf(v,v,s2);
            mx=fmaxf(mx,v); mn=fminf(mn,v);
          }
        s  += __shfl_xor(s,16,64);  s  += __shfl_xor(s,32,64);
        s2 += __shfl_xor(s2,16,64); s2 += __shfl_xor(s2,32,64);
        mx = fmaxf(mx, __shfl_xor(mx,16,64)); mx = fmaxf(mx, __shfl_xor(mx,32,64));
        mn = fminf(mn, __shfl_xor(mn,16,64)); mn = fminf(mn, __shfl_xor(mn,32,64));
        if (lane<16){
          int c = h*128 + wn*64+nt*16+lane;
          atomicAdd(&slots[(slot*256+c)*2+0], s);
          atomicAdd(&slots[(slot*256+c)*2+1], s2);
          size_t sidx = (size_t)mblk*2 + wm;         // global (b*1024+s)
          maxv[sidx*256 + c] = mx;
          minv[sidx*256 + c] = mn;
        }
      }
    }
  }
}

// ---------------------------------------------------------------------------
// Reduce 64 partial-sum slots -> per-channel scale/shift
// ---------------------------------------------------------------------------
__global__ void stats_kernel(const float* __restrict__ slots, const float* __restrict__ g,
                             const float* __restrict__ beta, float* __restrict__ ssOut,
                             int C, float inv_cnt){
  int c = threadIdx.x;
  if (c >= C) return;
  float s=0.f, s2=0.f;
  for (int k=0;k<64;++k){
    s  += slots[(k*C + c)*2 + 0];
    s2 += slots[(k*C + c)*2 + 1];
  }
  float m = s * inv_cnt;
  float v = fmaxf(s2 * inv_cnt - m*m, 0.f);
  float sc = rsqrtf(v + 1e-5f) * g[c];
  ssOut[c] = sc;
  ssOut[C + c] = beta[c] - m*sc;
}

// ---------------------------------------------------------------------------
// BN3 affine + relu on per-group max (min if scale<0); LDS-transposed so both
// the min/max reads and the (b,c,s)-layout writes are coalesced.
// ---------------------------------------------------------------------------
__global__ __launch_bounds__(256) void final_kernel(const float* __restrict__ minv,
                                                    const float* __restrict__ maxv,
                                                    const float* __restrict__ ss3,
                                                    float* __restrict__ out){
  __shared__ float tile[64][65];
  const int t = threadIdx.x;
  const int cb = blockIdx.x;   // 0..3  (64-channel block)
  const int sb = blockIdx.y;   // 0..15 (64-sample block)
  const int b  = blockIdx.z;   // 0..7
  const int w = t>>6, l = t&63;
  {
    int c = cb*64 + l;
    float sc = ss3[c], sh = ss3[256+c];
#pragma unroll
    for (int k=0;k<16;++k){
      int sl = k*4 + w;
      size_t mi = ((size_t)(b*1024 + sb*64 + sl))*256 + c;
      float v = (sc >= 0.f) ? maxv[mi] : minv[mi];
      tile[sl][l] = fmaxf(fmaf(v, sc, sh), 0.f);
    }
  }
  __syncthreads();
#pragma unroll
  for (int k=0;k<16;++k){
    int cl = k*4 + w;
    out[((size_t)(b*256 + cb*64 + cl))*1024 + sb*64 + l] = tile[l][cl];
  }
}

// ---------------------------------------------------------------------------
extern "C" void kernel_launch(void* const* d_in, const int* in_sizes, int n_in,
                              void* d_out, int out_size, void* d_ws, size_t ws_size,
                              hipStream_t stream){
  const float* xyz      = (const float*)d_in[0];
  const float* features = (const float*)d_in[1];
  const float* W1 = (const float*)d_in[2];
  const float* g1 = (const float*)d_in[3];
  const float* b1 = (const float*)d_in[4];
  const float* W2 = (const float*)d_in[5];
  const float* g2 = (const float*)d_in[6];
  const float* b2 = (const float*)d_in[7];
  const float* W3 = (const float*)d_in[8];
  const float* g3 = (const float*)d_in[9];
  const float* b3 = (const float*)d_in[10];
  float* out = (float*)d_out;

  char* ws = (char*)d_ws;
  size_t off = 0;
  auto alloc = [&](size_t bytes)->char*{
    char* p = ws + off;
    off = (off + bytes + 255) & ~(size_t)255;
    return p;
  };
  // total ~28 MB
  float* slots1 = (float*)alloc((size_t)64*128*2*4);
  float* slots2 = (float*)alloc((size_t)64*128*2*4);
  float* slots3 = (float*)alloc((size_t)64*256*2*4);
  float* ss1    = (float*)alloc(256*4);
  float* ss2    = (float*)alloc(256*4);
  float* ss3    = (float*)alloc(512*4);
  float* nxyz   = (float*)alloc((size_t)24576*4);
  int*   gi     = (int*)  alloc((size_t)M_*4);
  unsigned short* featT = (unsigned short*)alloc((size_t)B_*N_*CF_*2);
  unsigned short* Wt1   = (unsigned short*)alloc((size_t)128*160*2);
  unsigned short* Wt2   = (unsigned short*)alloc((size_t)128*128*2);
  unsigned short* Wt3   = (unsigned short*)alloc((size_t)256*128*2);
  float* minv = (float*)alloc((size_t)B_*S_*256*4);
  float* maxv = (float*)alloc((size_t)B_*S_*256*4);

  // zero the contiguous atomic-accumulator slots (256 KiB)
  hipMemsetAsync(slots1, 0, (size_t)(64*128*2 + 64*128*2 + 64*256*2)*4, stream);

  transpose_kernel<<<dim3(128,4,8), 256, 0, stream>>>(features, featT);
  wprep_kernel<<<64, 256, 0, stream>>>(W1, W2, W3, Wt1, Wt2, Wt3);
  fps_kernel<<<8, 256, 0, stream>>>(xyz, out, nxyz);
  qbp_kernel<<<2048, 256, 0, stream>>>(xyz, nxyz, gi);

  const float inv_cnt = 1.0f / (float)M_;
  mm_fused<1><<<4096, 256, 0, stream>>>(featT, Wt1, Wt2, Wt3, gi, xyz, nxyz,
                                        nullptr, nullptr, slots1, nullptr, nullptr);
  stats_kernel<<<1, 128, 0, stream>>>(slots1, g1, b1, ss1, 128, inv_cnt);
  mm_fused<2><<<4096, 256, 0, stream>>>(featT, Wt1, Wt2, Wt3, gi, xyz, nxyz,
                                        ss1, nullptr, slots2, nullptr, nullptr);
  stats_kernel<<<1, 128, 0, stream>>>(slots2, g2, b2, ss2, 128, inv_cnt);
  mm_fused<3><<<4096, 256, 0, stream>>>(featT, Wt1, Wt2, Wt3, gi, xyz, nxyz,
                                        ss1, ss2, slots3, minv, maxv);
  stats_kernel<<<1, 256, 0, stream>>>(slots3, g3, b3, ss3, 256, inv_cnt);
  final_kernel<<<dim3(4,16,8), 256, 0, stream>>>(minv, maxv, ss3, out + 24576);
}

// Round 7
// 1167.555 us; speedup vs baseline: 1.3214x; 1.0039x over previous
//
#include <hip/hip_runtime.h>

#define B_  8
#define N_  4096
#define S_  1024
#define K_  64
#define CF_ 128
#define M_  (B_*S_*K_)   // 524288 rows per layer

typedef __attribute__((ext_vector_type(8))) short bshort8;
typedef __attribute__((ext_vector_type(4))) float f32x4;
typedef __attribute__((ext_vector_type(4))) int   i32x4;
typedef __attribute__((ext_vector_type(2))) float f32x2;

__device__ __forceinline__ unsigned short f2bf(float f){
  unsigned int u = __float_as_uint(f);
  u = u + 0x7FFFu + ((u >> 16) & 1u);      // RTNE
  return (unsigned short)(u >> 16);
}
__device__ __forceinline__ float bf2f(unsigned short h){
  return __uint_as_float(((unsigned int)h) << 16);
}

// ---------------------------------------------------------------------------
// FPS v4: one block (256 thr = 4 waves, 1/SIMD) per batch.
// Semantics BITWISE-FROZEN (passing r4-r6): per-element plain rn sub/mul/add
// (fp contract OFF), fminf accumulate, strict-> argmax scanned in ascending
// point order (first-index tie-break), i = j*256+t point ownership.
// v4: update loop packed as float2 pairs -> v_pk_add/mul_f32 (VOP3P), halving
// VALU issue; packed ops are IEEE rn per element => bitwise identical.
// Tail unchanged from v3 (DPP pair-reduce, 4 packed slots, tree combine).
// ---------------------------------------------------------------------------
#define DPP_PAIR_STEP(CTRL)                                                     \
  {                                                                             \
    int _vi = __builtin_amdgcn_update_dpp(__float_as_int(best), __float_as_int(best), (CTRL), 0xF, 0xF, false); \
    int _ii = __builtin_amdgcn_update_dpp(bidx, bidx, (CTRL), 0xF, 0xF, false); \
    float _ov = __int_as_float(_vi);                                            \
    bool _tk = (_ov > best) || (_ov == best && _ii < bidx);                     \
    best = _tk ? _ov : best;                                                    \
    bidx = _tk ? _ii : bidx;                                                    \
  }

__global__ __launch_bounds__(256) void fps_kernel(const float* __restrict__ xyz,
                                                  float* __restrict__ nx_out,
                                                  float* __restrict__ nx_ws){
#pragma clang fp contract(off)
  __shared__ float sx[N_], sy[N_], sz[N_];
  __shared__ int   sidx[S_];
  __shared__ alignas(16) float redv[2][4];
  __shared__ alignas(16) int   redi[2][4];
  const int b = blockIdx.x, t = threadIdx.x;
  const int lane = t & 63, w = t >> 6;      // 4 waves
  const float* xb = xyz + (size_t)b*N_*3;
  f32x2 px[8], py[8], pz[8], dist[8];
#pragma unroll
  for (int j=0;j<8;++j){
    int i0 = (2*j)*256 + t, i1 = (2*j+1)*256 + t;
    float x0=xb[i0*3+0], y0=xb[i0*3+1], z0=xb[i0*3+2];
    float x1=xb[i1*3+0], y1=xb[i1*3+1], z1=xb[i1*3+2];
    px[j] = (f32x2){x0,x1}; py[j] = (f32x2){y0,y1}; pz[j] = (f32x2){z0,z1};
    dist[j] = (f32x2){1e10f,1e10f};
    sx[i0]=x0; sy[i0]=y0; sz[i0]=z0;
    sx[i1]=x1; sy[i1]=y1; sz[i1]=z1;
  }
  __syncthreads();
  int farthest = 0;
  for (int it=0; it<S_; ++it){
    if (t==0) sidx[it] = farthest;
    float cx = sx[farthest], cy = sy[farthest], cz = sz[farthest];
    f32x2 cx2 = (f32x2){cx,cx}, cy2 = (f32x2){cy,cy}, cz2 = (f32x2){cz,cz};
    float best = -1.0f; int bidx = 0;
#pragma unroll
    for (int j=0;j<8;++j){
      // per-element: ((dx*dx)+(dy*dy))+(dz*dz), plain rn (contract off)
      f32x2 dx = px[j] - cx2;
      f32x2 dy = py[j] - cy2;
      f32x2 dz = pz[j] - cz2;
      f32x2 d  = (dx*dx + dy*dy) + dz*dz;
      f32x2 nd;
      nd.x = fminf(dist[j].x, d.x);
      nd.y = fminf(dist[j].y, d.y);
      dist[j] = nd;
      // ascending-index scan: elem0 = (2j)*256+t, elem1 = (2j+1)*256+t
      bool tk0 = nd.x > best;
      best = tk0 ? nd.x : best;
      bidx = tk0 ? ((2*j)*256 + t) : bidx;
      bool tk1 = nd.y > best;
      best = tk1 ? nd.y : best;
      bidx = tk1 ? ((2*j+1)*256 + t) : bidx;
    }
    // wave64 pair-reduce via DPP; lane 63 ends with the wave result
    DPP_PAIR_STEP(0xB1);   // quad_perm [1,0,3,2]  (xor 1)
    DPP_PAIR_STEP(0x4E);   // quad_perm [2,3,0,1]  (xor 2)
    DPP_PAIR_STEP(0x124);  // row_ror:4
    DPP_PAIR_STEP(0x128);  // row_ror:8
    DPP_PAIR_STEP(0x142);  // row_bcast:15
    DPP_PAIR_STEP(0x143);  // row_bcast:31
    const int buf = it & 1;
    if (lane == 63){ redv[buf][w] = best; redi[buf][w] = bidx; }
    __syncthreads();
    f32x4 vv = *(const f32x4*)&redv[buf][0];   // one ds_read_b128
    i32x4 iv = *(const i32x4*)&redi[buf][0];   // one ds_read_b128
    // tree lex-max combine (associative; first-index tie-break preserved)
    float v01 = vv[0]; int i01 = iv[0];
    { bool tk = (vv[1] > v01) || (vv[1] == v01 && iv[1] < i01); v01 = tk?vv[1]:v01; i01 = tk?iv[1]:i01; }
    float v23 = vv[2]; int i23 = iv[2];
    { bool tk = (vv[3] > v23) || (vv[3] == v23 && iv[3] < i23); v23 = tk?vv[3]:v23; i23 = tk?iv[3]:i23; }
    { bool tk = (v23 > v01) || (v23 == v01 && i23 < i01); v01 = tk?v23:v01; i01 = tk?i23:i01; }
    farthest = i01;
  }
  __syncthreads();
  // write the 1024 selected centroids once, at the end
  for (int i=t; i<S_; i+=256){
    int id = sidx[i];
    size_t base = (size_t)(b*S_+i)*3;
    float vx=sx[id], vy=sy[id], vz=sz[id];
    nx_out[base+0]=vx; nx_out[base+1]=vy; nx_out[base+2]=vz;
    nx_ws[base+0]=vx;  nx_ws[base+1]=vy;  nx_ws[base+2]=vz;
  }
}

// ---------------------------------------------------------------------------
// Ball query: one wave per (b,s); ascending first-64 indices, pad with first.
// f64 membership (golden np ref evaluates in float64) — VERIFIED round 4.
// ---------------------------------------------------------------------------
__global__ __launch_bounds__(256) void qbp_kernel(const float* __restrict__ xyz,
                                                  const float* __restrict__ nx,
                                                  int* __restrict__ gi){
  const double R2 = 0.2*0.2;   // 0.04000000000000001 (f64)
  int gtid = blockIdx.x*256 + threadIdx.x;
  int wid = gtid >> 6, lane = gtid & 63;
  int b = wid >> 10, s = wid & 1023;
  const float* xb = xyz + (size_t)b*N_*3;
  const float* c  = nx + (size_t)(b*S_+s)*3;
  double cx=(double)c[0], cy=(double)c[1], cz=(double)c[2];
  double cc = cx*cx + cy*cy + cz*cz;
  int* g = gi + (size_t)(b*S_+s)*K_;
  int count = 0, first = -1;
  for (int ch=0; ch<64 && count<K_; ++ch){
    int i = ch*64 + lane;
    double x = (double)xb[i*3+0], y = (double)xb[i*3+1], z = (double)xb[i*3+2];
    double e  = cx*x + cy*y + cz*z;
    double pp = x*x + y*y + z*z;
    double d  = -2.0*e + cc + pp;
    bool keep = !(d > R2);
    unsigned long long bal = __ballot(keep);
    int pos = count + __builtin_popcountll(bal & ((1ull<<lane)-1ull));
    if (keep && pos < K_) g[pos] = i;
    if (first < 0 && bal) first = ch*64 + (int)__builtin_ctzll(bal);
    count += __builtin_popcountll(bal);
  }
  if (count < K_){
    int p = count + lane;
    if (p < K_) g[p] = first;
  }
}

// ---------------------------------------------------------------------------
// features (B,128,4096) f32 -> featT (B,4096,128) bf16
// ---------------------------------------------------------------------------
__global__ __launch_bounds__(256) void transpose_kernel(const float* __restrict__ f,
                                                        unsigned short* __restrict__ ft){
  __shared__ float tile[32][33];
  int b = blockIdx.z, ct = blockIdx.y, nt = blockIdx.x;
  int tx = threadIdx.x & 31, ty = threadIdx.x >> 5;
#pragma unroll
  for (int r=0; r<32; r+=8)
    tile[ty+r][tx] = f[((size_t)(b*128 + ct*32 + ty + r))*4096 + nt*32 + tx];
  __syncthreads();
#pragma unroll
  for (int r=0; r<32; r+=8){
    int n = nt*32 + ty + r, cc = ct*32 + tx;
    ft[((size_t)b*4096 + n)*128 + cc] = f2bf(tile[tx][ty+r]);
  }
}

// ---------------------------------------------------------------------------
// Weights -> bf16 [n][k]; layer-1 K permuted to [feat(0..127), dxyz(128..130), 0-pad..159]
// ---------------------------------------------------------------------------
__global__ void wprep_kernel(const float* __restrict__ W1, const float* __restrict__ W2,
                             const float* __restrict__ W3,
                             unsigned short* __restrict__ Wt1, unsigned short* __restrict__ Wt2,
                             unsigned short* __restrict__ Wt3){
  int t = blockIdx.x*blockDim.x + threadIdx.x;
  int stride = gridDim.x*blockDim.x;
  for (int idx=t; idx<128*160; idx+=stride){
    int n = idx/160, k = idx-(idx/160)*160;
    float v = 0.f;
    if (k < 128) v = W1[(k+3)*128 + n];
    else if (k < 131) v = W1[(k-128)*128 + n];
    Wt1[idx] = f2bf(v);
  }
  for (int idx=t; idx<128*128; idx+=stride){
    int n = idx>>7, k = idx&127;
    Wt2[idx] = f2bf(W2[k*128+n]);
  }
  for (int idx=t; idx<256*128; idx+=stride){
    int n = idx>>7, k = idx&127;
    Wt3[idx] = f2bf(W3[k*256+n]);
  }
}

// ---------------------------------------------------------------------------
// Fused recompute GEMM chain per 128-row slab. No y1/y2 in global memory.
// PHASE 1: GEMM1 -> col sums1
// PHASE 2: GEMM1 -> BN1+ReLU(LDS) -> GEMM2 -> col sums2
// PHASE 3: GEMM1 -> BN1 -> GEMM2 -> BN2 -> GEMM3 (2 N-halves) -> sums3 + min/max over K
// ---------------------------------------------------------------------------
template<int PHASE>
__global__ __launch_bounds__(256,2) void mm_fused(
    const unsigned short* __restrict__ featT,
    const unsigned short* __restrict__ Wt1,
    const unsigned short* __restrict__ Wt2,
    const unsigned short* __restrict__ Wt3,
    const int* __restrict__ gi,
    const float* __restrict__ xyz,
    const float* __restrict__ nxyz,
    const float* __restrict__ ss1,
    const float* __restrict__ ss2,
    float* __restrict__ slots,
    float* __restrict__ minv,
    float* __restrict__ maxv)
{
  __shared__ alignas(16) unsigned short At[128*40];
  __shared__ alignas(16) unsigned short Bt[128*40];
  __shared__ alignas(16) unsigned short Y[(PHASE>=2)?(128*136):16];
  __shared__ int giL[128];

  const int t = threadIdx.x;
  const int mblk = blockIdx.x;
  const int b = mblk >> 9;                 // 512 slabs per batch
  const int lane = t&63, wave = t>>6;
  const int wm = wave>>1, wn = wave&1;
  const int lrow = lane&15, quad = lane>>4;
  const int slot = mblk & 63;

  if (t<128) giL[t] = gi[(size_t)mblk*128 + t];
  __syncthreads();

  f32x4 acc[4][4];
  const f32x4 z4 = {0.f,0.f,0.f,0.f};
#pragma unroll
  for (int i=0;i<4;++i)
#pragma unroll
    for (int j=0;j<4;++j) acc[i][j]=z4;

  // ---------------- GEMM1: A = gathered [feat | dxyz | pad], K=160 ----------
  for (int ch=0; ch<5; ++ch){
#pragma unroll
    for (int half=0; half<2; ++half){
      int sl = t + half*256; int r = sl>>2, p = sl&3;
      *(bshort8*)&Bt[r*40+p*8] = *(const bshort8*)(Wt1 + r*160 + ch*32 + p*8);
      if (ch < 4){
        int i = giL[r];
        *(bshort8*)&At[r*40+p*8] =
            *(const bshort8*)(featT + ((size_t)b*N_ + i)*CF_ + ch*32 + p*8);
      } else {
        union { bshort8 v; unsigned short u[8]; } o;
#pragma unroll
        for (int e=0;e<8;++e) o.u[e]=0;
        if (p==0){
          int i = giL[r];
          int s = ((mblk*128 + r) >> 6) & 1023;
          const float* pp = xyz  + ((size_t)b*N_ + i)*3;
          const float* qq = nxyz + (size_t)(b*S_ + s)*3;
          o.u[0] = f2bf(__fsub_rn(pp[0],qq[0]));
          o.u[1] = f2bf(__fsub_rn(pp[1],qq[1]));
          o.u[2] = f2bf(__fsub_rn(pp[2],qq[2]));
        }
        *(bshort8*)&At[r*40+p*8] = o.v;
      }
    }
    __syncthreads();
    bshort8 af[4], bfr[4];
#pragma unroll
    for (int mt=0; mt<4; ++mt) af[mt]  = *(const bshort8*)&At[(wm*64+mt*16+lrow)*40 + quad*8];
#pragma unroll
    for (int nt=0; nt<4; ++nt) bfr[nt] = *(const bshort8*)&Bt[(wn*64+nt*16+lrow)*40 + quad*8];
#pragma unroll
    for (int mt=0; mt<4; ++mt)
#pragma unroll
      for (int nt=0; nt<4; ++nt)
        acc[mt][nt] = __builtin_amdgcn_mfma_f32_16x16x32_bf16(af[mt], bfr[nt], acc[mt][nt], 0,0,0);
    __syncthreads();
  }

  if constexpr (PHASE==1){
#pragma unroll
    for (int nt=0; nt<4; ++nt){
      float s=0.f, s2=0.f;
#pragma unroll
      for (int mt=0; mt<4; ++mt)
#pragma unroll
        for (int r=0; r<4; ++r){ float v=acc[mt][nt][r]; s+=v; s2=fmaf(v,v,s2); }
      s  += __shfl_xor(s,16,64);  s  += __shfl_xor(s,32,64);
      s2 += __shfl_xor(s2,16,64); s2 += __shfl_xor(s2,32,64);
      if (lane<16){
        int c = wn*64+nt*16+lane;
        atomicAdd(&slots[(slot*128+c)*2+0], s);
        atomicAdd(&slots[(slot*128+c)*2+1], s2);
      }
    }
    return;
  }

  if constexpr (PHASE>=2){
    // ---- BN1 + ReLU -> Y (C-layout: col=lane&15, row=quad*4+reg) ----
#pragma unroll
    for (int nt=0; nt<4; ++nt){
      int c = wn*64+nt*16+lrow;
      float sc = ss1[c], sh = ss1[128+c];
#pragma unroll
      for (int mt=0; mt<4; ++mt)
#pragma unroll
        for (int r=0; r<4; ++r){
          int row = wm*64+mt*16+quad*4+r;
          Y[row*136 + c] = f2bf(fmaxf(fmaf(acc[mt][nt][r], sc, sh), 0.f));
        }
    }
    __syncthreads();

    // ---------------- GEMM2: A = Y (z1), K=128 ----------------
#pragma unroll
    for (int i=0;i<4;++i)
#pragma unroll
      for (int j=0;j<4;++j) acc[i][j]=z4;
    for (int ch=0; ch<4; ++ch){
#pragma unroll
      for (int half=0; half<2; ++half){
        int sl = t + half*256; int r = sl>>2, p = sl&3;
        *(bshort8*)&Bt[r*40+p*8] = *(const bshort8*)(Wt2 + r*128 + ch*32 + p*8);
      }
      __syncthreads();
      bshort8 af[4], bfr[4];
#pragma unroll
      for (int mt=0; mt<4; ++mt) af[mt]  = *(const bshort8*)&Y[(wm*64+mt*16+lrow)*136 + ch*32 + quad*8];
#pragma unroll
      for (int nt=0; nt<4; ++nt) bfr[nt] = *(const bshort8*)&Bt[(wn*64+nt*16+lrow)*40 + quad*8];
#pragma unroll
      for (int mt=0; mt<4; ++mt)
#pragma unroll
        for (int nt=0; nt<4; ++nt)
          acc[mt][nt] = __builtin_amdgcn_mfma_f32_16x16x32_bf16(af[mt], bfr[nt], acc[mt][nt], 0,0,0);
      __syncthreads();
    }
  }

  if constexpr (PHASE==2){
#pragma unroll
    for (int nt=0; nt<4; ++nt){
      float s=0.f, s2=0.f;
#pragma unroll
      for (int mt=0; mt<4; ++mt)
#pragma unroll
        for (int r=0; r<4; ++r){ float v=acc[mt][nt][r]; s+=v; s2=fmaf(v,v,s2); }
      s  += __shfl_xor(s,16,64);  s  += __shfl_xor(s,32,64);
      s2 += __shfl_xor(s2,16,64); s2 += __shfl_xor(s2,32,64);
      if (lane<16){
        int c = wn*64+nt*16+lane;
        atomicAdd(&slots[(slot*128+c)*2+0], s);
        atomicAdd(&slots[(slot*128+c)*2+1], s2);
      }
    }
    return;
  }

  if constexpr (PHASE==3){
    // ---- BN2 + ReLU -> Y (overwrite) ----
#pragma unroll
    for (int nt=0; nt<4; ++nt){
      int c = wn*64+nt*16+lrow;
      float sc = ss2[c], sh = ss2[128+c];
#pragma unroll
      for (int mt=0; mt<4; ++mt)
#pragma unroll
        for (int r=0; r<4; ++r){
          int row = wm*64+mt*16+quad*4+r;
          Y[row*136 + c] = f2bf(fmaxf(fmaf(acc[mt][nt][r], sc, sh), 0.f));
        }
    }
    __syncthreads();

    // ---------------- GEMM3: A = Y (z2), Nout=256 in two halves ------------
    for (int h=0; h<2; ++h){
#pragma unroll
      for (int i=0;i<4;++i)
#pragma unroll
        for (int j=0;j<4;++j) acc[i][j]=z4;
      for (int ch=0; ch<4; ++ch){
#pragma unroll
        for (int half=0; half<2; ++half){
          int sl = t + half*256; int r = sl>>2, p = sl&3;
          *(bshort8*)&Bt[r*40+p*8] =
              *(const bshort8*)(Wt3 + ((size_t)(h*128+r))*128 + ch*32 + p*8);
        }
        __syncthreads();
        bshort8 af[4], bfr[4];
#pragma unroll
        for (int mt=0; mt<4; ++mt) af[mt]  = *(const bshort8*)&Y[(wm*64+mt*16+lrow)*136 + ch*32 + quad*8];
#pragma unroll
        for (int nt=0; nt<4; ++nt) bfr[nt] = *(const bshort8*)&Bt[(wn*64+nt*16+lrow)*40 + quad*8];
#pragma unroll
        for (int mt=0; mt<4; ++mt)
#pragma unroll
          for (int nt=0; nt<4; ++nt)
            acc[mt][nt] = __builtin_amdgcn_mfma_f32_16x16x32_bf16(af[mt], bfr[nt], acc[mt][nt], 0,0,0);
        __syncthreads();
      }
      // epilogue: sums3 + per-(b,s) min/max over the 64 rows of each group
#pragma unroll
      for (int nt=0; nt<4; ++nt){
        float s=0.f, s2=0.f, mx=-3.0e38f, mn=3.0e38f;
#pragma unroll
        for (int mt=0; mt<4; ++mt)
#pragma unroll
          for (int r=0; r<4; ++r){
            float v=acc[mt][nt][r];
            s+=v; s2=fmaf(v,v,s2);
            mx=fmaxf(mx,v); mn=fminf(mn,v);
          }
        s  += __shfl_xor(s,16,64);  s  += __shfl_xor(s,32,64);
        s2 += __shfl_xor(s2,16,64); s2 += __shfl_xor(s2,32,64);
        mx = fmaxf(mx, __shfl_xor(mx,16,64)); mx = fmaxf(mx, __shfl_xor(mx,32,64));
        mn = fminf(mn, __shfl_xor(mn,16,64)); mn = fminf(mn, __shfl_xor(mn,32,64));
        if (lane<16){
          int c = h*128 + wn*64+nt*16+lane;
          atomicAdd(&slots[(slot*256+c)*2+0], s);
          atomicAdd(&slots[(slot*256+c)*2+1], s2);
          size_t sidx = (size_t)mblk*2 + wm;         // global (b*1024+s)
          maxv[sidx*256 + c] = mx;
          minv[sidx*256 + c] = mn;
        }
      }
    }
  }
}

// ---------------------------------------------------------------------------
// Reduce 64 partial-sum slots -> per-channel scale/shift
// ---------------------------------------------------------------------------
__global__ void stats_kernel(const float* __restrict__ slots, const float* __restrict__ g,
                             const float* __restrict__ beta, float* __restrict__ ssOut,
                             int C, float inv_cnt){
  int c = threadIdx.x;
  if (c >= C) return;
  float s=0.f, s2=0.f;
  for (int k=0;k<64;++k){
    s  += slots[(k*C + c)*2 + 0];
    s2 += slots[(k*C + c)*2 + 1];
  }
  float m = s * inv_cnt;
  float v = fmaxf(s2 * inv_cnt - m*m, 0.f);
  float sc = rsqrtf(v + 1e-5f) * g[c];
  ssOut[c] = sc;
  ssOut[C + c] = beta[c] - m*sc;
}

// ---------------------------------------------------------------------------
// BN3 affine + relu on per-group max (min if scale<0); LDS-transposed so both
// the min/max reads and the (b,c,s)-layout writes are coalesced.
// ---------------------------------------------------------------------------
__global__ __launch_bounds__(256) void final_kernel(const float* __restrict__ minv,
                                                    const float* __restrict__ maxv,
                                                    const float* __restrict__ ss3,
                                                    float* __restrict__ out){
  __shared__ float tile[64][65];
  const int t = threadIdx.x;
  const int cb = blockIdx.x;   // 0..3  (64-channel block)
  const int sb = blockIdx.y;   // 0..15 (64-sample block)
  const int b  = blockIdx.z;   // 0..7
  const int w = t>>6, l = t&63;
  {
    int c = cb*64 + l;
    float sc = ss3[c], sh = ss3[256+c];
#pragma unroll
    for (int k=0;k<16;++k){
      int sl = k*4 + w;
      size_t mi = ((size_t)(b*1024 + sb*64 + sl))*256 + c;
      float v = (sc >= 0.f) ? maxv[mi] : minv[mi];
      tile[sl][l] = fmaxf(fmaf(v, sc, sh), 0.f);
    }
  }
  __syncthreads();
#pragma unroll
  for (int k=0;k<16;++k){
    int cl = k*4 + w;
    out[((size_t)(b*256 + cb*64 + cl))*1024 + sb*64 + l] = tile[l][cl];
  }
}

// ---------------------------------------------------------------------------
extern "C" void kernel_launch(void* const* d_in, const int* in_sizes, int n_in,
                              void* d_out, int out_size, void* d_ws, size_t ws_size,
                              hipStream_t stream){
  const float* xyz      = (const float*)d_in[0];
  const float* features = (const float*)d_in[1];
  const float* W1 = (const float*)d_in[2];
  const float* g1 = (const float*)d_in[3];
  const float* b1 = (const float*)d_in[4];
  const float* W2 = (const float*)d_in[5];
  const float* g2 = (const float*)d_in[6];
  const float* b2 = (const float*)d_in[7];
  const float* W3 = (const float*)d_in[8];
  const float* g3 = (const float*)d_in[9];
  const float* b3 = (const float*)d_in[10];
  float* out = (float*)d_out;

  char* ws = (char*)d_ws;
  size_t off = 0;
  auto alloc = [&](size_t bytes)->char*{
    char* p = ws + off;
    off = (off + bytes + 255) & ~(size_t)255;
    return p;
  };
  // total ~28 MB
  float* slots1 = (float*)alloc((size_t)64*128*2*4);
  float* slots2 = (float*)alloc((size_t)64*128*2*4);
  float* slots3 = (float*)alloc((size_t)64*256*2*4);
  float* ss1    = (float*)alloc(256*4);
  float* ss2    = (float*)alloc(256*4);
  float* ss3    = (float*)alloc(512*4);
  float* nxyz   = (float*)alloc((size_t)24576*4);
  int*   gi     = (int*)  alloc((size_t)M_*4);
  unsigned short* featT = (unsigned short*)alloc((size_t)B_*N_*CF_*2);
  unsigned short* Wt1   = (unsigned short*)alloc((size_t)128*160*2);
  unsigned short* Wt2   = (unsigned short*)alloc((size_t)128*128*2);
  unsigned short* Wt3   = (unsigned short*)alloc((size_t)256*128*2);
  float* minv = (float*)alloc((size_t)B_*S_*256*4);
  float* maxv = (float*)alloc((size_t)B_*S_*256*4);

  // zero the contiguous atomic-accumulator slots (256 KiB)
  hipMemsetAsync(slots1, 0, (size_t)(64*128*2 + 64*128*2 + 64*256*2)*4, stream);

  transpose_kernel<<<dim3(128,4,8), 256, 0, stream>>>(features, featT);
  wprep_kernel<<<64, 256, 0, stream>>>(W1, W2, W3, Wt1, Wt2, Wt3);
  fps_kernel<<<8, 256, 0, stream>>>(xyz, out, nxyz);
  qbp_kernel<<<2048, 256, 0, stream>>>(xyz, nxyz, gi);

  const float inv_cnt = 1.0f / (float)M_;
  mm_fused<1><<<4096, 256, 0, stream>>>(featT, Wt1, Wt2, Wt3, gi, xyz, nxyz,
                                        nullptr, nullptr, slots1, nullptr, nullptr);
  stats_kernel<<<1, 128, 0, stream>>>(slots1, g1, b1, ss1, 128, inv_cnt);
  mm_fused<2><<<4096, 256, 0, stream>>>(featT, Wt1, Wt2, Wt3, gi, xyz, nxyz,
                                        ss1, nullptr, slots2, nullptr, nullptr);
  stats_kernel<<<1, 128, 0, stream>>>(slots2, g2, b2, ss2, 128, inv_cnt);
  mm_fused<3><<<4096, 256, 0, stream>>>(featT, Wt1, Wt2, Wt3, gi, xyz, nxyz,
                                        ss1, ss2, slots3, minv, maxv);
  stats_kernel<<<1, 256, 0, stream>>>(slots3, g3, b3, ss3, 256, inv_cnt);
  final_kernel<<<dim3(4,16,8), 256, 0, stream>>>(minv, maxv, ss3, out + 24576);
}